// Round 1
// baseline (708.324 us; speedup 1.0000x reference)
//
#include <hip/hip_runtime.h>
#include <math.h>

#define N_NODES 50000
#define N_EDGES 800000
#define ETOT    (N_EDGES + N_NODES)   // self-loops appended
#define GGRAPHS 64
#define EPS_BN  1e-5f

// ---------------- CSR build ----------------

__global__ void k_hist(const int* __restrict__ ei, int* __restrict__ cnt) {
    int e = blockIdx.x * 256 + threadIdx.x;
    if (e >= ETOT) return;
    int d = (e < N_EDGES) ? ei[N_EDGES + e] : (e - N_EDGES);
    atomicAdd(&cnt[d], 1);
}

__global__ void k_scan_local(const int* __restrict__ cnt, int* __restrict__ offs,
                             int* __restrict__ bsums) {
    __shared__ int s[256];
    int t = threadIdx.x, idx = blockIdx.x * 256 + t;
    int v = (idx < N_NODES) ? cnt[idx] : 0;
    s[t] = v; __syncthreads();
    for (int d2 = 1; d2 < 256; d2 <<= 1) {
        int add = (t >= d2) ? s[t - d2] : 0;
        __syncthreads();
        s[t] += add;
        __syncthreads();
    }
    if (idx < N_NODES) offs[idx] = s[t] - v;       // local exclusive
    if (t == 255) bsums[blockIdx.x] = s[255];
}

__global__ void k_scan_sums(int* __restrict__ bsums, int nb) {
    __shared__ int s[256];
    int t = threadIdx.x;
    int v = (t < nb) ? bsums[t] : 0;
    s[t] = v; __syncthreads();
    for (int d2 = 1; d2 < 256; d2 <<= 1) {
        int add = (t >= d2) ? s[t - d2] : 0;
        __syncthreads();
        s[t] += add;
        __syncthreads();
    }
    if (t < nb) bsums[t] = s[t] - v;               // exclusive
}

__global__ void k_scan_add(int* __restrict__ offs, int* __restrict__ cursor,
                           const int* __restrict__ bsums) {
    int idx = blockIdx.x * 256 + threadIdx.x;
    if (idx < N_NODES) {
        int o = offs[idx] + bsums[blockIdx.x];
        offs[idx] = o;
        cursor[idx] = o;
    }
    if (idx == 0) offs[N_NODES] = ETOT;
}

__global__ void k_fill(const int* __restrict__ ei, int* __restrict__ cursor,
                       int* __restrict__ csr) {
    int e = blockIdx.x * 256 + threadIdx.x;
    if (e >= ETOT) return;
    int s, d;
    if (e < N_EDGES) { s = ei[e]; d = ei[N_EDGES + e]; }
    else             { s = d = e - N_EDGES; }
    int pos = atomicAdd(&cursor[d], 1);
    csr[pos] = s;
}

// ---------------- GEMM1: h1 = x @ W1, scores es1/ed1 ----------------
// block: 256 threads = 4 waves; wave handles 4 nodes; lanes cover 256 cols (4 each).

#define W1PAD 260

__global__ __launch_bounds__(256, 2)
void k_gemm1(const float* __restrict__ x, const float* __restrict__ W1,
             const float* __restrict__ a_s, const float* __restrict__ a_d,
             float* __restrict__ h1, float* __restrict__ es1, float* __restrict__ ed1) {
    __shared__ float wl[64 * W1PAD];
    __shared__ float xT[64][16];
    __shared__ float asl[256], adl[256];
    int t = threadIdx.x;
    for (int i = t; i < 64 * 256; i += 256) wl[(i >> 8) * W1PAD + (i & 255)] = W1[i];
    asl[t] = a_s[t]; adl[t] = a_d[t];
    int wave = t >> 6, lane = t & 63;
    for (int base = blockIdx.x * 16; base < N_NODES; base += gridDim.x * 16) {
        __syncthreads();
        for (int j = 0; j < 4; ++j) {
            int id = t + j * 256;
            int nd = id >> 6, k = id & 63;
            int node = base + nd;
            xT[k][nd] = (node < N_NODES) ? x[node * 64 + k] : 0.f;
        }
        __syncthreads();
        float acc[4][4];
#pragma unroll
        for (int i = 0; i < 4; ++i)
#pragma unroll
            for (int j = 0; j < 4; ++j) acc[i][j] = 0.f;
#pragma unroll 4
        for (int k = 0; k < 64; ++k) {
            float4 wv = *(const float4*)&wl[k * W1PAD + lane * 4];
            float4 xv = *(const float4*)&xT[k][wave * 4];
#pragma unroll
            for (int i = 0; i < 4; ++i) {
                float xi = (i == 0) ? xv.x : (i == 1) ? xv.y : (i == 2) ? xv.z : xv.w;
                acc[i][0] += xi * wv.x; acc[i][1] += xi * wv.y;
                acc[i][2] += xi * wv.z; acc[i][3] += xi * wv.w;
            }
        }
        int head = lane >> 4;
        float4 av = *(const float4*)&asl[head * 64 + (lane & 15) * 4];
        float4 dv = *(const float4*)&adl[head * 64 + (lane & 15) * 4];
#pragma unroll
        for (int i = 0; i < 4; ++i) {
            int node = base + wave * 4 + i;
            float ps = acc[i][0] * av.x + acc[i][1] * av.y + acc[i][2] * av.z + acc[i][3] * av.w;
            float pd = acc[i][0] * dv.x + acc[i][1] * dv.y + acc[i][2] * dv.z + acc[i][3] * dv.w;
#pragma unroll
            for (int m = 1; m <= 8; m <<= 1) {
                ps += __shfl_xor(ps, m);
                pd += __shfl_xor(pd, m);
            }
            if (node < N_NODES) {
                float4 hv = make_float4(acc[i][0], acc[i][1], acc[i][2], acc[i][3]);
                *(float4*)&h1[(size_t)node * 256 + lane * 4] = hv;
                if ((lane & 15) == 0) {
                    es1[node * 4 + head] = ps;
                    ed1[node * 4 + head] = pd;
                }
            }
        }
    }
}

// ---------------- GAT1 aggregate + bias + BN + ELU ----------------
// block per dst node; 256 threads = 256 channels; head = tid/64.

__global__ __launch_bounds__(256)
void k_gat1(const float* __restrict__ h1, const float* __restrict__ es1,
            const float* __restrict__ ed1, const int* __restrict__ offs,
            const int* __restrict__ csr, const float* __restrict__ b1,
            const float* __restrict__ g1, const float* __restrict__ be1,
            const float* __restrict__ m1, const float* __restrict__ v1,
            float* __restrict__ hb) {
    int d = blockIdx.x;
    int t = threadIdx.x;
    __shared__ float red[256];
    int start = offs[d], end = offs[d + 1];
    int deg = end - start;
    // phase 1: per-head max (thread t: head t&3, slots t>>2 + 64i)
    int h = t & 3;
    float edv = ed1[d * 4 + h];
    float mx = -1e30f;
    for (int j = t >> 2; j < deg; j += 64) {
        int s = csr[start + j];
        float e = es1[s * 4 + h] + edv;
        e = (e > 0.f) ? e : 0.2f * e;
        mx = fmaxf(mx, e);
    }
    red[t] = mx; __syncthreads();
    for (int s2 = 128; s2 >= 4; s2 >>= 1) {
        if (t < s2) red[t] = fmaxf(red[t], red[t + s2]);
        __syncthreads();
    }
    // phase 2: unnormalized accumulate, divide at end
    int hc = t >> 6;
    float mH = red[hc];
    float edv2 = ed1[d * 4 + hc];
    float acc = 0.f, dn = 0.f;
    for (int j = 0; j < deg; ++j) {
        int s = csr[start + j];
        float e = es1[s * 4 + hc] + edv2;
        e = (e > 0.f) ? e : 0.2f * e;
        float p = __expf(e - mH);
        dn += p;
        acc += p * h1[(size_t)s * 256 + t];
    }
    float o = acc / dn + b1[t];
    o = (o - m1[t]) * rsqrtf(v1[t] + EPS_BN) * g1[t] + be1[t];
    o = (o > 0.f) ? o : expm1f(o);
    hb[(size_t)d * 256 + t] = o;
}

// ---------------- GEMM2: h2 = hb @ W2, scores es2/ed2 ----------------
// block: 4 waves; wave handles 2 nodes; lane = output col.

#define W2PAD 260

__global__ __launch_bounds__(256, 2)
void k_gemm2(const float* __restrict__ hb, const float* __restrict__ W2,
             const float* __restrict__ a_s, const float* __restrict__ a_d,
             float* __restrict__ h2, float* __restrict__ es2, float* __restrict__ ed2) {
    __shared__ float w2t[64 * W2PAD];   // [col][k] padded
    __shared__ float xs[8][256];
    __shared__ float asl[64], adl[64];
    int t = threadIdx.x;
    for (int i = t; i < 256 * 64; i += 256) {
        int k = i >> 6, c = i & 63;
        w2t[c * W2PAD + k] = W2[i];
    }
    if (t < 64) { asl[t] = a_s[t]; adl[t] = a_d[t]; }
    int wave = t >> 6, lane = t & 63;
    for (int base = blockIdx.x * 8; base < N_NODES; base += gridDim.x * 8) {
        __syncthreads();
        for (int j = 0; j < 8; ++j) {
            int id = t + j * 256;
            int nd = id >> 8, k = id & 255;
            int node = base + nd;
            xs[nd][k] = (node < N_NODES) ? hb[(size_t)node * 256 + k] : 0.f;
        }
        __syncthreads();
        int n0 = wave * 2;
        float acc0 = 0.f, acc1 = 0.f;
#pragma unroll 4
        for (int kg = 0; kg < 64; ++kg) {
            float4 wv = *(const float4*)&w2t[lane * W2PAD + kg * 4];
            float4 x0 = *(const float4*)&xs[n0][kg * 4];
            float4 x1 = *(const float4*)&xs[n0 + 1][kg * 4];
            acc0 += wv.x * x0.x + wv.y * x0.y + wv.z * x0.z + wv.w * x0.w;
            acc1 += wv.x * x1.x + wv.y * x1.y + wv.z * x1.z + wv.w * x1.w;
        }
        float pa0 = acc0 * asl[lane], pd0 = acc0 * adl[lane];
        float pa1 = acc1 * asl[lane], pd1 = acc1 * adl[lane];
#pragma unroll
        for (int m = 1; m <= 32; m <<= 1) {
            pa0 += __shfl_xor(pa0, m); pd0 += __shfl_xor(pd0, m);
            pa1 += __shfl_xor(pa1, m); pd1 += __shfl_xor(pd1, m);
        }
        int node0 = base + n0, node1 = node0 + 1;
        if (node0 < N_NODES) {
            h2[(size_t)node0 * 64 + lane] = acc0;
            if (lane == 0) { es2[node0] = pa0; ed2[node0] = pd0; }
        }
        if (node1 < N_NODES) {
            h2[(size_t)node1 * 64 + lane] = acc1;
            if (lane == 0) { es2[node1] = pa1; ed2[node1] = pd1; }
        }
    }
}

// ---------------- GAT2 aggregate + bias + BN ----------------
// wave per dst node; lane = channel.

__global__ __launch_bounds__(256)
void k_gat2(const float* __restrict__ h2, const float* __restrict__ es2,
            const float* __restrict__ ed2, const int* __restrict__ offs,
            const int* __restrict__ csr, const float* __restrict__ b2,
            const float* __restrict__ g2, const float* __restrict__ be2,
            const float* __restrict__ m2, const float* __restrict__ v2,
            float* __restrict__ out2) {
    int wave = threadIdx.x >> 6, lane = threadIdx.x & 63;
    int d = blockIdx.x * 4 + wave;
    if (d >= N_NODES) return;
    int start = offs[d], end = offs[d + 1];
    int deg = end - start;
    float edv = ed2[d];
    float mx = -1e30f;
    for (int j = lane; j < deg; j += 64) {
        int s = csr[start + j];
        float e = es2[s] + edv;
        e = (e > 0.f) ? e : 0.2f * e;
        mx = fmaxf(mx, e);
    }
#pragma unroll
    for (int m = 1; m <= 32; m <<= 1) mx = fmaxf(mx, __shfl_xor(mx, m));
    float acc = 0.f, dn = 0.f;
    for (int j = 0; j < deg; ++j) {
        int s = csr[start + j];
        float e = es2[s] + edv;
        e = (e > 0.f) ? e : 0.2f * e;
        float p = __expf(e - mx);
        dn += p;
        acc += p * h2[(size_t)s * 64 + lane];
    }
    float o = acc / dn + b2[lane];
    o = (o - m2[lane]) * rsqrtf(v2[lane] + EPS_BN) * g2[lane] + be2[lane];
    out2[(size_t)d * 64 + lane] = o;
}

// ---------------- mean pool per graph ----------------

__device__ int lower_bound_i(const int* a, int n, int key) {
    int lo = 0, hi = n;
    while (lo < hi) {
        int mid = (lo + hi) >> 1;
        if (a[mid] < key) lo = mid + 1; else hi = mid;
    }
    return lo;
}

__global__ __launch_bounds__(256)
void k_pool(const float* __restrict__ out2, const int* __restrict__ batch,
            float* __restrict__ pooled) {
    int g = blockIdx.x;
    __shared__ int ssh[2];
    __shared__ float red[256];
    if (threadIdx.x == 0) {
        ssh[0] = lower_bound_i(batch, N_NODES, g);
        ssh[1] = lower_bound_i(batch, N_NODES, g + 1);
    }
    __syncthreads();
    int start = ssh[0], end = ssh[1];
    int t = threadIdx.x, sub = t >> 6, lane = t & 63;
    float acc = 0.f;
    for (int i = start + sub; i < end; i += 4) acc += out2[(size_t)i * 64 + lane];
    red[t] = acc; __syncthreads();
    if (t < 64) {
        float s = red[t] + red[t + 64] + red[t + 128] + red[t + 192];
        int cnt = end - start;
        pooled[g * 64 + t] = s / (float)((cnt > 0) ? cnt : 1);
    }
}

// ---------------- MLP head + log_softmax ----------------

__global__ void k_head(const float* __restrict__ pooled, const float* __restrict__ lw1,
                       const float* __restrict__ lb1, const float* __restrict__ lw2,
                       const float* __restrict__ lb2, float* __restrict__ out) {
    int g = threadIdx.x;
    if (g >= GGRAPHS) return;
    float p[64];
#pragma unroll
    for (int c = 0; c < 64; ++c) p[c] = pooled[g * 64 + c];
    float z0 = lb2[0], z1 = lb2[1], z2 = lb2[2];
    for (int j = 0; j < 32; ++j) {
        float hj = lb1[j];
#pragma unroll
        for (int c = 0; c < 64; ++c) hj += p[c] * lw1[c * 32 + j];
        hj = fmaxf(hj, 0.f);
        z0 += hj * lw2[j * 3 + 0];
        z1 += hj * lw2[j * 3 + 1];
        z2 += hj * lw2[j * 3 + 2];
    }
    float m = fmaxf(z0, fmaxf(z1, z2));
    float lse = logf(expf(z0 - m) + expf(z1 - m) + expf(z2 - m)) + m;
    out[g * 3 + 0] = z0 - lse;
    out[g * 3 + 1] = z1 - lse;
    out[g * 3 + 2] = z2 - lse;
}

// ---------------- launch ----------------

extern "C" void kernel_launch(void* const* d_in, const int* in_sizes, int n_in,
                              void* d_out, int out_size, void* d_ws, size_t ws_size,
                              hipStream_t stream) {
    (void)in_sizes; (void)n_in; (void)out_size; (void)ws_size;
    const float* x    = (const float*)d_in[0];
    const int*   ei   = (const int*)d_in[1];
    const int*   batch= (const int*)d_in[2];
    const float* W1   = (const float*)d_in[3];
    const float* a_s1 = (const float*)d_in[4];
    const float* a_d1 = (const float*)d_in[5];
    const float* b1   = (const float*)d_in[6];
    const float* g1   = (const float*)d_in[7];
    const float* be1  = (const float*)d_in[8];
    const float* m1   = (const float*)d_in[9];
    const float* v1   = (const float*)d_in[10];
    const float* W2   = (const float*)d_in[11];
    const float* a_s2 = (const float*)d_in[12];
    const float* a_d2 = (const float*)d_in[13];
    const float* b2   = (const float*)d_in[14];
    const float* g2   = (const float*)d_in[15];
    const float* be2  = (const float*)d_in[16];
    const float* m2   = (const float*)d_in[17];
    const float* v2   = (const float*)d_in[18];
    const float* lw1  = (const float*)d_in[19];
    const float* lb1  = (const float*)d_in[20];
    const float* lw2  = (const float*)d_in[21];
    const float* lb2  = (const float*)d_in[22];
    float* out = (float*)d_out;

    char* ws = (char*)d_ws;
    size_t off = 0;
    auto alloc = [&](size_t bytes) -> void* {
        void* p = ws + off;
        off += (bytes + 255) & ~(size_t)255;
        return p;
    };
    float* h1   = (float*)alloc((size_t)N_NODES * 256 * 4);
    float* hb   = (float*)alloc((size_t)N_NODES * 256 * 4);
    float* es1  = (float*)alloc((size_t)N_NODES * 4 * 4);
    float* ed1  = (float*)alloc((size_t)N_NODES * 4 * 4);
    float* es2  = (float*)alloc((size_t)N_NODES * 4);
    float* ed2  = (float*)alloc((size_t)N_NODES * 4);
    int*   cnt  = (int*)alloc((size_t)N_NODES * 4);
    int*   offs = (int*)alloc((size_t)(N_NODES + 1) * 4);
    int*   curs = (int*)alloc((size_t)N_NODES * 4);
    int*   csr  = (int*)alloc((size_t)ETOT * 4);
    int*   bsums= (int*)alloc(256 * 4);
    // overlays on dead h1 (h1 unused after k_gat1):
    float* h2     = h1;
    float* out2   = h1 + (size_t)N_NODES * 64;
    float* pooled = h1 + (size_t)N_NODES * 128;

    const int nscan = (N_NODES + 255) / 256;   // 196
    const int nedge = (ETOT + 255) / 256;      // 3321

    hipMemsetAsync(cnt, 0, (size_t)N_NODES * 4, stream);
    k_hist<<<nedge, 256, 0, stream>>>(ei, cnt);
    k_scan_local<<<nscan, 256, 0, stream>>>(cnt, offs, bsums);
    k_scan_sums<<<1, 256, 0, stream>>>(bsums, nscan);
    k_scan_add<<<nscan, 256, 0, stream>>>(offs, curs, bsums);
    k_fill<<<nedge, 256, 0, stream>>>(ei, curs, csr);

    k_gemm1<<<512, 256, 0, stream>>>(x, W1, a_s1, a_d1, h1, es1, ed1);
    k_gat1<<<N_NODES, 256, 0, stream>>>(h1, es1, ed1, offs, csr, b1, g1, be1, m1, v1, hb);
    k_gemm2<<<512, 256, 0, stream>>>(hb, W2, a_s2, a_d2, h2, es2, ed2);
    k_gat2<<<(N_NODES + 3) / 4, 256, 0, stream>>>(h2, es2, ed2, offs, csr, b2, g2, be2, m2, v2, out2);
    k_pool<<<GGRAPHS, 256, 0, stream>>>(out2, batch, pooled);
    k_head<<<1, 64, 0, stream>>>(pooled, lw1, lb1, lw2, lb2, out);
}

// Round 2
// 598.719 us; speedup vs baseline: 1.1831x; 1.1831x over previous
//
#include <hip/hip_runtime.h>
#include <math.h>

#define N_NODES 50000
#define N_EDGES 800000
#define ETOT    (N_EDGES + N_NODES)   // self-loops appended
#define GGRAPHS 64
#define EPS_BN  1e-5f

__device__ __forceinline__ unsigned short f2bf(float f) {
    union { float f; unsigned u; } v; v.f = f;
    unsigned r = v.u + 0x7fffu + ((v.u >> 16) & 1u);   // round-nearest-even
    return (unsigned short)(r >> 16);
}
__device__ __forceinline__ float bf2f(unsigned short h) {
    union { unsigned u; float f; } v; v.u = ((unsigned)h) << 16;
    return v.f;
}

// ---------------- CSR build ----------------

__global__ void k_hist(const int* __restrict__ ei, int* __restrict__ cnt) {
    int e = blockIdx.x * 256 + threadIdx.x;
    if (e >= ETOT) return;
    int d = (e < N_EDGES) ? ei[N_EDGES + e] : (e - N_EDGES);
    atomicAdd(&cnt[d], 1);
}

__global__ void k_scan_local(const int* __restrict__ cnt, int* __restrict__ offs,
                             int* __restrict__ bsums) {
    __shared__ int s[256];
    int t = threadIdx.x, idx = blockIdx.x * 256 + t;
    int v = (idx < N_NODES) ? cnt[idx] : 0;
    s[t] = v; __syncthreads();
    for (int d2 = 1; d2 < 256; d2 <<= 1) {
        int add = (t >= d2) ? s[t - d2] : 0;
        __syncthreads();
        s[t] += add;
        __syncthreads();
    }
    if (idx < N_NODES) offs[idx] = s[t] - v;       // local exclusive
    if (t == 255) bsums[blockIdx.x] = s[255];
}

__global__ void k_scan_sums(int* __restrict__ bsums, int nb) {
    __shared__ int s[256];
    int t = threadIdx.x;
    int v = (t < nb) ? bsums[t] : 0;
    s[t] = v; __syncthreads();
    for (int d2 = 1; d2 < 256; d2 <<= 1) {
        int add = (t >= d2) ? s[t - d2] : 0;
        __syncthreads();
        s[t] += add;
        __syncthreads();
    }
    if (t < nb) bsums[t] = s[t] - v;               // exclusive
}

__global__ void k_scan_add(int* __restrict__ offs, int* __restrict__ cursor,
                           const int* __restrict__ bsums) {
    int idx = blockIdx.x * 256 + threadIdx.x;
    if (idx < N_NODES) {
        int o = offs[idx] + bsums[blockIdx.x];
        offs[idx] = o;
        cursor[idx] = o;
    }
    if (idx == 0) offs[N_NODES] = ETOT;
}

__global__ void k_fill(const int* __restrict__ ei, int* __restrict__ cursor,
                       int* __restrict__ csr) {
    int e = blockIdx.x * 256 + threadIdx.x;
    if (e >= ETOT) return;
    int s, d;
    if (e < N_EDGES) { s = ei[e]; d = ei[N_EDGES + e]; }
    else             { s = d = e - N_EDGES; }
    int pos = atomicAdd(&cursor[d], 1);
    csr[pos] = s;
}

// ---------------- GEMM1: h1(bf16) = x @ W1, scores es1/ed1 ----------------
// block: 256 threads = 4 waves; wave handles 4 nodes; lanes cover 256 cols (4 each).

#define W1PAD 260

__global__ __launch_bounds__(256, 2)
void k_gemm1(const float* __restrict__ x, const float* __restrict__ W1,
             const float* __restrict__ a_s, const float* __restrict__ a_d,
             unsigned short* __restrict__ h1, float* __restrict__ es1, float* __restrict__ ed1) {
    __shared__ float wl[64 * W1PAD];
    __shared__ float xT[64][16];
    __shared__ float asl[256], adl[256];
    int t = threadIdx.x;
    for (int i = t; i < 64 * 256; i += 256) wl[(i >> 8) * W1PAD + (i & 255)] = W1[i];
    asl[t] = a_s[t]; adl[t] = a_d[t];
    int wave = t >> 6, lane = t & 63;
    for (int base = blockIdx.x * 16; base < N_NODES; base += gridDim.x * 16) {
        __syncthreads();
        for (int j = 0; j < 4; ++j) {
            int id = t + j * 256;
            int nd = id >> 6, k = id & 63;
            int node = base + nd;
            xT[k][nd] = (node < N_NODES) ? x[node * 64 + k] : 0.f;
        }
        __syncthreads();
        float acc[4][4];
#pragma unroll
        for (int i = 0; i < 4; ++i)
#pragma unroll
            for (int j = 0; j < 4; ++j) acc[i][j] = 0.f;
#pragma unroll 4
        for (int k = 0; k < 64; ++k) {
            float4 wv = *(const float4*)&wl[k * W1PAD + lane * 4];
            float4 xv = *(const float4*)&xT[k][wave * 4];
#pragma unroll
            for (int i = 0; i < 4; ++i) {
                float xi = (i == 0) ? xv.x : (i == 1) ? xv.y : (i == 2) ? xv.z : xv.w;
                acc[i][0] += xi * wv.x; acc[i][1] += xi * wv.y;
                acc[i][2] += xi * wv.z; acc[i][3] += xi * wv.w;
            }
        }
        int head = lane >> 4;
        float4 av = *(const float4*)&asl[head * 64 + (lane & 15) * 4];
        float4 dv = *(const float4*)&adl[head * 64 + (lane & 15) * 4];
#pragma unroll
        for (int i = 0; i < 4; ++i) {
            int node = base + wave * 4 + i;
            float ps = acc[i][0] * av.x + acc[i][1] * av.y + acc[i][2] * av.z + acc[i][3] * av.w;
            float pd = acc[i][0] * dv.x + acc[i][1] * dv.y + acc[i][2] * dv.z + acc[i][3] * dv.w;
#pragma unroll
            for (int m = 1; m <= 8; m <<= 1) {
                ps += __shfl_xor(ps, m);
                pd += __shfl_xor(pd, m);
            }
            if (node < N_NODES) {
                ushort4 hv;
                hv.x = f2bf(acc[i][0]); hv.y = f2bf(acc[i][1]);
                hv.z = f2bf(acc[i][2]); hv.w = f2bf(acc[i][3]);
                *(ushort4*)&h1[(size_t)node * 256 + lane * 4] = hv;
                if ((lane & 15) == 0) {
                    es1[node * 4 + head] = ps;
                    ed1[node * 4 + head] = pd;
                }
            }
        }
    }
}

// ---------------- GAT1 aggregate + bias + BN + ELU ----------------
// wave per dst node (4 nodes/block); lane l owns channels 4l..4l+3, head = l>>4.

__global__ __launch_bounds__(256)
void k_gat1(const unsigned short* __restrict__ h1, const float* __restrict__ es1,
            const float* __restrict__ ed1, const int* __restrict__ offs,
            const int* __restrict__ csr, const float* __restrict__ b1,
            const float* __restrict__ g1, const float* __restrict__ be1,
            const float* __restrict__ m1, const float* __restrict__ v1,
            float* __restrict__ hb) {
    int wave = threadIdx.x >> 6, lane = threadIdx.x & 63;
    int d = blockIdx.x * 4 + wave;
    if (d >= N_NODES) return;
    int start = offs[d], deg = offs[d + 1] - start;
    // phase 1: per-head max; lane handles head lane&3, edges strided by 16
    int hp = lane & 3;
    float edv = ed1[d * 4 + hp];
    float mx = -1e30f;
    for (int j = lane >> 2; j < deg; j += 16) {
        int s = csr[start + j];
        float e = es1[s * 4 + hp] + edv;
        e = (e > 0.f) ? e : 0.2f * e;
        mx = fmaxf(mx, e);
    }
#pragma unroll
    for (int m = 4; m <= 32; m <<= 1) mx = fmaxf(mx, __shfl_xor(mx, m));
    // lane hc (hc in 0..3) now holds the max of head hc
    int hc = lane >> 4;
    float mH = __shfl(mx, hc);
    float edv2 = ed1[d * 4 + hc];
    float a0 = 0.f, a1 = 0.f, a2 = 0.f, a3 = 0.f, dn = 0.f;
    for (int j = 0; j < deg; ++j) {
        int s = csr[start + j];
        float e = es1[s * 4 + hc] + edv2;
        e = (e > 0.f) ? e : 0.2f * e;
        float p = __expf(e - mH);
        dn += p;
        ushort4 hv = *(const ushort4*)&h1[(size_t)s * 256 + lane * 4];
        a0 += p * bf2f(hv.x); a1 += p * bf2f(hv.y);
        a2 += p * bf2f(hv.z); a3 += p * bf2f(hv.w);
    }
    float inv = 1.f / dn;
    int c = lane * 4;
    float4 bv = *(const float4*)&b1[c];
    float4 gv = *(const float4*)&g1[c];
    float4 ev = *(const float4*)&be1[c];
    float4 mv = *(const float4*)&m1[c];
    float4 vv = *(const float4*)&v1[c];
    float o0 = a0 * inv + bv.x, o1 = a1 * inv + bv.y, o2 = a2 * inv + bv.z, o3 = a3 * inv + bv.w;
    o0 = (o0 - mv.x) * rsqrtf(vv.x + EPS_BN) * gv.x + ev.x;
    o1 = (o1 - mv.y) * rsqrtf(vv.y + EPS_BN) * gv.y + ev.y;
    o2 = (o2 - mv.z) * rsqrtf(vv.z + EPS_BN) * gv.z + ev.z;
    o3 = (o3 - mv.w) * rsqrtf(vv.w + EPS_BN) * gv.w + ev.w;
    o0 = (o0 > 0.f) ? o0 : expm1f(o0);
    o1 = (o1 > 0.f) ? o1 : expm1f(o1);
    o2 = (o2 > 0.f) ? o2 : expm1f(o2);
    o3 = (o3 > 0.f) ? o3 : expm1f(o3);
    *(float4*)&hb[(size_t)d * 256 + c] = make_float4(o0, o1, o2, o3);
}

// ---------------- GEMM2: h2(bf16) = hb @ W2, scores es2/ed2 ----------------
// block: 4 waves; wave handles 2 nodes; lane = output col.

#define W2PAD 260

__global__ __launch_bounds__(256, 2)
void k_gemm2(const float* __restrict__ hb, const float* __restrict__ W2,
             const float* __restrict__ a_s, const float* __restrict__ a_d,
             unsigned short* __restrict__ h2, float* __restrict__ es2, float* __restrict__ ed2) {
    __shared__ float w2t[64 * W2PAD];   // [col][k] padded
    __shared__ float xs[8][256];
    __shared__ float asl[64], adl[64];
    int t = threadIdx.x;
    for (int i = t; i < 256 * 64; i += 256) {
        int k = i >> 6, c = i & 63;
        w2t[c * W2PAD + k] = W2[i];
    }
    if (t < 64) { asl[t] = a_s[t]; adl[t] = a_d[t]; }
    int wave = t >> 6, lane = t & 63;
    for (int base = blockIdx.x * 8; base < N_NODES; base += gridDim.x * 8) {
        __syncthreads();
        for (int j = 0; j < 8; ++j) {
            int id = t + j * 256;
            int nd = id >> 8, k = id & 255;
            int node = base + nd;
            xs[nd][k] = (node < N_NODES) ? hb[(size_t)node * 256 + k] : 0.f;
        }
        __syncthreads();
        int n0 = wave * 2;
        float acc0 = 0.f, acc1 = 0.f;
#pragma unroll 4
        for (int kg = 0; kg < 64; ++kg) {
            float4 wv = *(const float4*)&w2t[lane * W2PAD + kg * 4];
            float4 x0 = *(const float4*)&xs[n0][kg * 4];
            float4 x1 = *(const float4*)&xs[n0 + 1][kg * 4];
            acc0 += wv.x * x0.x + wv.y * x0.y + wv.z * x0.z + wv.w * x0.w;
            acc1 += wv.x * x1.x + wv.y * x1.y + wv.z * x1.z + wv.w * x1.w;
        }
        float pa0 = acc0 * asl[lane], pd0 = acc0 * adl[lane];
        float pa1 = acc1 * asl[lane], pd1 = acc1 * adl[lane];
#pragma unroll
        for (int m = 1; m <= 32; m <<= 1) {
            pa0 += __shfl_xor(pa0, m); pd0 += __shfl_xor(pd0, m);
            pa1 += __shfl_xor(pa1, m); pd1 += __shfl_xor(pd1, m);
        }
        int node0 = base + n0, node1 = node0 + 1;
        if (node0 < N_NODES) {
            h2[(size_t)node0 * 64 + lane] = f2bf(acc0);
            if (lane == 0) { es2[node0] = pa0; ed2[node0] = pd0; }
        }
        if (node1 < N_NODES) {
            h2[(size_t)node1 * 64 + lane] = f2bf(acc1);
            if (lane == 0) { es2[node1] = pa1; ed2[node1] = pd1; }
        }
    }
}

// ---------------- GAT2 aggregate + bias + BN ----------------
// wave per dst node; lane = channel.

__global__ __launch_bounds__(256)
void k_gat2(const unsigned short* __restrict__ h2, const float* __restrict__ es2,
            const float* __restrict__ ed2, const int* __restrict__ offs,
            const int* __restrict__ csr, const float* __restrict__ b2,
            const float* __restrict__ g2, const float* __restrict__ be2,
            const float* __restrict__ m2, const float* __restrict__ v2,
            float* __restrict__ out2) {
    int wave = threadIdx.x >> 6, lane = threadIdx.x & 63;
    int d = blockIdx.x * 4 + wave;
    if (d >= N_NODES) return;
    int start = offs[d], deg = offs[d + 1] - start;
    float edv = ed2[d];
    float mx = -1e30f;
    for (int j = lane; j < deg; j += 64) {
        int s = csr[start + j];
        float e = es2[s] + edv;
        e = (e > 0.f) ? e : 0.2f * e;
        mx = fmaxf(mx, e);
    }
#pragma unroll
    for (int m = 1; m <= 32; m <<= 1) mx = fmaxf(mx, __shfl_xor(mx, m));
    float acc = 0.f, dn = 0.f;
    for (int j = 0; j < deg; ++j) {
        int s = csr[start + j];
        float e = es2[s] + edv;
        e = (e > 0.f) ? e : 0.2f * e;
        float p = __expf(e - mx);
        dn += p;
        acc += p * bf2f(h2[(size_t)s * 64 + lane]);
    }
    float o = acc / dn + b2[lane];
    o = (o - m2[lane]) * rsqrtf(v2[lane] + EPS_BN) * g2[lane] + be2[lane];
    out2[(size_t)d * 64 + lane] = o;
}

// ---------------- mean pool per graph ----------------

__device__ int lower_bound_i(const int* a, int n, int key) {
    int lo = 0, hi = n;
    while (lo < hi) {
        int mid = (lo + hi) >> 1;
        if (a[mid] < key) lo = mid + 1; else hi = mid;
    }
    return lo;
}

__global__ __launch_bounds__(256)
void k_pool(const float* __restrict__ out2, const int* __restrict__ batch,
            float* __restrict__ pooled) {
    int g = blockIdx.x;
    __shared__ int ssh[2];
    __shared__ float red[256];
    if (threadIdx.x == 0) {
        ssh[0] = lower_bound_i(batch, N_NODES, g);
        ssh[1] = lower_bound_i(batch, N_NODES, g + 1);
    }
    __syncthreads();
    int start = ssh[0], end = ssh[1];
    int t = threadIdx.x, sub = t >> 6, lane = t & 63;
    float acc = 0.f;
    for (int i = start + sub; i < end; i += 4) acc += out2[(size_t)i * 64 + lane];
    red[t] = acc; __syncthreads();
    if (t < 64) {
        float s = red[t] + red[t + 64] + red[t + 128] + red[t + 192];
        int cnt = end - start;
        pooled[g * 64 + t] = s / (float)((cnt > 0) ? cnt : 1);
    }
}

// ---------------- MLP head + log_softmax ----------------

__global__ void k_head(const float* __restrict__ pooled, const float* __restrict__ lw1,
                       const float* __restrict__ lb1, const float* __restrict__ lw2,
                       const float* __restrict__ lb2, float* __restrict__ out) {
    int g = threadIdx.x;
    if (g >= GGRAPHS) return;
    float p[64];
#pragma unroll
    for (int c = 0; c < 64; ++c) p[c] = pooled[g * 64 + c];
    float z0 = lb2[0], z1 = lb2[1], z2 = lb2[2];
    for (int j = 0; j < 32; ++j) {
        float hj = lb1[j];
#pragma unroll
        for (int c = 0; c < 64; ++c) hj += p[c] * lw1[c * 32 + j];
        hj = fmaxf(hj, 0.f);
        z0 += hj * lw2[j * 3 + 0];
        z1 += hj * lw2[j * 3 + 1];
        z2 += hj * lw2[j * 3 + 2];
    }
    float m = fmaxf(z0, fmaxf(z1, z2));
    float lse = logf(expf(z0 - m) + expf(z1 - m) + expf(z2 - m)) + m;
    out[g * 3 + 0] = z0 - lse;
    out[g * 3 + 1] = z1 - lse;
    out[g * 3 + 2] = z2 - lse;
}

// ---------------- launch ----------------

extern "C" void kernel_launch(void* const* d_in, const int* in_sizes, int n_in,
                              void* d_out, int out_size, void* d_ws, size_t ws_size,
                              hipStream_t stream) {
    (void)in_sizes; (void)n_in; (void)out_size; (void)ws_size;
    const float* x    = (const float*)d_in[0];
    const int*   ei   = (const int*)d_in[1];
    const int*   batch= (const int*)d_in[2];
    const float* W1   = (const float*)d_in[3];
    const float* a_s1 = (const float*)d_in[4];
    const float* a_d1 = (const float*)d_in[5];
    const float* b1   = (const float*)d_in[6];
    const float* g1   = (const float*)d_in[7];
    const float* be1  = (const float*)d_in[8];
    const float* m1   = (const float*)d_in[9];
    const float* v1   = (const float*)d_in[10];
    const float* W2   = (const float*)d_in[11];
    const float* a_s2 = (const float*)d_in[12];
    const float* a_d2 = (const float*)d_in[13];
    const float* b2   = (const float*)d_in[14];
    const float* g2   = (const float*)d_in[15];
    const float* be2  = (const float*)d_in[16];
    const float* m2   = (const float*)d_in[17];
    const float* v2   = (const float*)d_in[18];
    const float* lw1  = (const float*)d_in[19];
    const float* lb1  = (const float*)d_in[20];
    const float* lw2  = (const float*)d_in[21];
    const float* lb2  = (const float*)d_in[22];
    float* out = (float*)d_out;

    char* ws = (char*)d_ws;
    size_t off = 0;
    auto alloc = [&](size_t bytes) -> void* {
        void* p = ws + off;
        off += (bytes + 255) & ~(size_t)255;
        return p;
    };
    unsigned short* h1 = (unsigned short*)alloc((size_t)N_NODES * 256 * 2);  // bf16
    float* hb   = (float*)alloc((size_t)N_NODES * 256 * 4);
    unsigned short* h2 = (unsigned short*)alloc((size_t)N_NODES * 64 * 2);   // bf16
    float* out2 = (float*)alloc((size_t)N_NODES * 64 * 4);
    float* es1  = (float*)alloc((size_t)N_NODES * 4 * 4);
    float* ed1  = (float*)alloc((size_t)N_NODES * 4 * 4);
    float* es2  = (float*)alloc((size_t)N_NODES * 4);
    float* ed2  = (float*)alloc((size_t)N_NODES * 4);
    float* pooled = (float*)alloc((size_t)GGRAPHS * 64 * 4);
    int*   cnt  = (int*)alloc((size_t)N_NODES * 4);
    int*   offs = (int*)alloc((size_t)(N_NODES + 1) * 4);
    int*   curs = (int*)alloc((size_t)N_NODES * 4);
    int*   csr  = (int*)alloc((size_t)ETOT * 4);
    int*   bsums= (int*)alloc(256 * 4);

    const int nscan = (N_NODES + 255) / 256;   // 196
    const int nedge = (ETOT + 255) / 256;      // 3321

    hipMemsetAsync(cnt, 0, (size_t)N_NODES * 4, stream);
    k_hist<<<nedge, 256, 0, stream>>>(ei, cnt);
    k_scan_local<<<nscan, 256, 0, stream>>>(cnt, offs, bsums);
    k_scan_sums<<<1, 256, 0, stream>>>(bsums, nscan);
    k_scan_add<<<nscan, 256, 0, stream>>>(offs, curs, bsums);
    k_fill<<<nedge, 256, 0, stream>>>(ei, curs, csr);

    k_gemm1<<<512, 256, 0, stream>>>(x, W1, a_s1, a_d1, h1, es1, ed1);
    k_gat1<<<(N_NODES + 3) / 4, 256, 0, stream>>>(h1, es1, ed1, offs, csr, b1, g1, be1, m1, v1, hb);
    k_gemm2<<<512, 256, 0, stream>>>(hb, W2, a_s2, a_d2, h2, es2, ed2);
    k_gat2<<<(N_NODES + 3) / 4, 256, 0, stream>>>(h2, es2, ed2, offs, csr, b2, g2, be2, m2, v2, out2);
    k_pool<<<GGRAPHS, 256, 0, stream>>>(out2, batch, pooled);
    k_head<<<1, 64, 0, stream>>>(pooled, lw1, lb1, lw2, lb2, out);
}

// Round 3
// 507.977 us; speedup vs baseline: 1.3944x; 1.1786x over previous
//
#include <hip/hip_runtime.h>
#include <math.h>

#define N_NODES 50000
#define N_EDGES 800000
#define ETOT    (N_EDGES + N_NODES)   // self-loops appended
#define GGRAPHS 64
#define EPS_BN  1e-5f

__device__ __forceinline__ unsigned short f2bf(float f) {
    union { float f; unsigned u; } v; v.f = f;
    unsigned r = v.u + 0x7fffu + ((v.u >> 16) & 1u);   // round-nearest-even
    return (unsigned short)(r >> 16);
}
__device__ __forceinline__ float bf_lo(unsigned u) {
    union { unsigned u; float f; } v; v.u = u << 16; return v.f;
}
__device__ __forceinline__ float bf_hi(unsigned u) {
    union { unsigned u; float f; } v; v.u = u & 0xffff0000u; return v.f;
}

// ---------------- CSR build ----------------

__global__ void k_hist(const int* __restrict__ ei, int* __restrict__ cnt) {
    int e = blockIdx.x * 256 + threadIdx.x;
    if (e >= ETOT) return;
    int d = (e < N_EDGES) ? ei[N_EDGES + e] : (e - N_EDGES);
    atomicAdd(&cnt[d], 1);
}

__global__ void k_scan_local(const int* __restrict__ cnt, int* __restrict__ offs,
                             int* __restrict__ bsums) {
    __shared__ int s[256];
    int t = threadIdx.x, idx = blockIdx.x * 256 + t;
    int v = (idx < N_NODES) ? cnt[idx] : 0;
    s[t] = v; __syncthreads();
    for (int d2 = 1; d2 < 256; d2 <<= 1) {
        int add = (t >= d2) ? s[t - d2] : 0;
        __syncthreads();
        s[t] += add;
        __syncthreads();
    }
    if (idx < N_NODES) offs[idx] = s[t] - v;       // local exclusive
    if (t == 255) bsums[blockIdx.x] = s[255];
}

__global__ void k_scan_sums(int* __restrict__ bsums, int nb) {
    __shared__ int s[256];
    int t = threadIdx.x;
    int v = (t < nb) ? bsums[t] : 0;
    s[t] = v; __syncthreads();
    for (int d2 = 1; d2 < 256; d2 <<= 1) {
        int add = (t >= d2) ? s[t - d2] : 0;
        __syncthreads();
        s[t] += add;
        __syncthreads();
    }
    if (t < nb) bsums[t] = s[t] - v;               // exclusive
}

__global__ void k_scan_add(int* __restrict__ offs, int* __restrict__ cursor,
                           const int* __restrict__ bsums) {
    int idx = blockIdx.x * 256 + threadIdx.x;
    if (idx < N_NODES) {
        int o = offs[idx] + bsums[blockIdx.x];
        offs[idx] = o;
        cursor[idx] = o;
    }
    if (idx == 0) offs[N_NODES] = ETOT;
}

__global__ void k_fill(const int* __restrict__ ei, int* __restrict__ cursor,
                       int* __restrict__ csr) {
    int e = blockIdx.x * 256 + threadIdx.x;
    if (e >= ETOT) return;
    int s, d;
    if (e < N_EDGES) { s = ei[e]; d = ei[N_EDGES + e]; }
    else             { s = d = e - N_EDGES; }
    int pos = atomicAdd(&cursor[d], 1);
    csr[pos] = s;
}

// ---------------- GEMM1: h1(bf16) = x @ W1, scores es1/ed1 ----------------

#define W1PAD 260

__global__ __launch_bounds__(256, 2)
void k_gemm1(const float* __restrict__ x, const float* __restrict__ W1,
             const float* __restrict__ a_s, const float* __restrict__ a_d,
             unsigned short* __restrict__ h1, float* __restrict__ es1, float* __restrict__ ed1) {
    __shared__ float wl[64 * W1PAD];
    __shared__ float xT[64][16];
    __shared__ float asl[256], adl[256];
    int t = threadIdx.x;
    for (int i = t; i < 64 * 256; i += 256) wl[(i >> 8) * W1PAD + (i & 255)] = W1[i];
    asl[t] = a_s[t]; adl[t] = a_d[t];
    int wave = t >> 6, lane = t & 63;
    for (int base = blockIdx.x * 16; base < N_NODES; base += gridDim.x * 16) {
        __syncthreads();
        for (int j = 0; j < 4; ++j) {
            int id = t + j * 256;
            int nd = id >> 6, k = id & 63;
            int node = base + nd;
            xT[k][nd] = (node < N_NODES) ? x[node * 64 + k] : 0.f;
        }
        __syncthreads();
        float acc[4][4];
#pragma unroll
        for (int i = 0; i < 4; ++i)
#pragma unroll
            for (int j = 0; j < 4; ++j) acc[i][j] = 0.f;
#pragma unroll 4
        for (int k = 0; k < 64; ++k) {
            float4 wv = *(const float4*)&wl[k * W1PAD + lane * 4];
            float4 xv = *(const float4*)&xT[k][wave * 4];
#pragma unroll
            for (int i = 0; i < 4; ++i) {
                float xi = (i == 0) ? xv.x : (i == 1) ? xv.y : (i == 2) ? xv.z : xv.w;
                acc[i][0] += xi * wv.x; acc[i][1] += xi * wv.y;
                acc[i][2] += xi * wv.z; acc[i][3] += xi * wv.w;
            }
        }
        int head = lane >> 4;
        float4 av = *(const float4*)&asl[head * 64 + (lane & 15) * 4];
        float4 dv = *(const float4*)&adl[head * 64 + (lane & 15) * 4];
#pragma unroll
        for (int i = 0; i < 4; ++i) {
            int node = base + wave * 4 + i;
            float ps = acc[i][0] * av.x + acc[i][1] * av.y + acc[i][2] * av.z + acc[i][3] * av.w;
            float pd = acc[i][0] * dv.x + acc[i][1] * dv.y + acc[i][2] * dv.z + acc[i][3] * dv.w;
#pragma unroll
            for (int m = 1; m <= 8; m <<= 1) {
                ps += __shfl_xor(ps, m);
                pd += __shfl_xor(pd, m);
            }
            if (node < N_NODES) {
                ushort4 hv;
                hv.x = f2bf(acc[i][0]); hv.y = f2bf(acc[i][1]);
                hv.z = f2bf(acc[i][2]); hv.w = f2bf(acc[i][3]);
                *(ushort4*)&h1[(size_t)node * 256 + lane * 4] = hv;
                if ((lane & 15) == 0) {
                    es1[node * 4 + head] = ps;
                    ed1[node * 4 + head] = pd;
                }
            }
        }
    }
}

// ---------------- GAT1 aggregate + bias + BN + ELU ----------------
// wave per dst node (4/block). Phase 2: half-wave covers a 256-ch row
// (uint4 = 8 bf16/lane), 2 edges per iteration, ×2 unrolled (4 in flight).

__global__ __launch_bounds__(256)
void k_gat1(const unsigned short* __restrict__ h1, const float* __restrict__ es1,
            const float* __restrict__ ed1, const int* __restrict__ offs,
            const int* __restrict__ csr, const float* __restrict__ b1,
            const float* __restrict__ g1, const float* __restrict__ be1,
            const float* __restrict__ m1, const float* __restrict__ v1,
            float* __restrict__ hb) {
    int wave = threadIdx.x >> 6, lane = threadIdx.x & 63;
    int d = blockIdx.x * 4 + wave;
    if (d >= N_NODES) return;
    int start = offs[d], deg = offs[d + 1] - start;
    // phase 1: per-head max; lane handles head lane&3, edges strided by 16
    int hp = lane & 3;
    float edv = ed1[d * 4 + hp];
    float mx = -1e30f;
    for (int j = lane >> 2; j < deg; j += 16) {
        int s = csr[start + j];
        float e = es1[s * 4 + hp] + edv;
        e = (e > 0.f) ? e : 0.2f * e;
        mx = fmaxf(mx, e);
    }
#pragma unroll
    for (int m = 4; m <= 32; m <<= 1) mx = fmaxf(mx, __shfl_xor(mx, m));
    // phase 2
    int half = lane >> 5;          // which edge of the pair
    int cg = lane & 31;            // channel group: channels cg*8 .. cg*8+7
    int ch = cg * 8;
    int hc = cg >> 3;              // head of these channels
    float mH = __shfl(mx, hc);
    float edv2 = ed1[d * 4 + hc];
    float a[8];
#pragma unroll
    for (int k = 0; k < 8; ++k) a[k] = 0.f;
    float dn = 0.f;
    int j = 0;
    for (; j + 4 <= deg; j += 4) {
        int s0 = csr[start + j + half];
        int s1 = csr[start + j + 2 + half];
        float e0 = es1[s0 * 4 + hc] + edv2;
        float e1 = es1[s1 * 4 + hc] + edv2;
        uint4 r0 = *(const uint4*)&h1[(size_t)s0 * 256 + ch];
        uint4 r1 = *(const uint4*)&h1[(size_t)s1 * 256 + ch];
        e0 = (e0 > 0.f) ? e0 : 0.2f * e0;
        e1 = (e1 > 0.f) ? e1 : 0.2f * e1;
        float p0 = __expf(e0 - mH);
        float p1 = __expf(e1 - mH);
        dn += p0 + p1;
        a[0] += p0 * bf_lo(r0.x); a[1] += p0 * bf_hi(r0.x);
        a[2] += p0 * bf_lo(r0.y); a[3] += p0 * bf_hi(r0.y);
        a[4] += p0 * bf_lo(r0.z); a[5] += p0 * bf_hi(r0.z);
        a[6] += p0 * bf_lo(r0.w); a[7] += p0 * bf_hi(r0.w);
        a[0] += p1 * bf_lo(r1.x); a[1] += p1 * bf_hi(r1.x);
        a[2] += p1 * bf_lo(r1.y); a[3] += p1 * bf_hi(r1.y);
        a[4] += p1 * bf_lo(r1.z); a[5] += p1 * bf_hi(r1.z);
        a[6] += p1 * bf_lo(r1.w); a[7] += p1 * bf_hi(r1.w);
    }
    for (; j + 2 <= deg; j += 2) {
        int s0 = csr[start + j + half];
        float e0 = es1[s0 * 4 + hc] + edv2;
        uint4 r0 = *(const uint4*)&h1[(size_t)s0 * 256 + ch];
        e0 = (e0 > 0.f) ? e0 : 0.2f * e0;
        float p0 = __expf(e0 - mH);
        dn += p0;
        a[0] += p0 * bf_lo(r0.x); a[1] += p0 * bf_hi(r0.x);
        a[2] += p0 * bf_lo(r0.y); a[3] += p0 * bf_hi(r0.y);
        a[4] += p0 * bf_lo(r0.z); a[5] += p0 * bf_hi(r0.z);
        a[6] += p0 * bf_lo(r0.w); a[7] += p0 * bf_hi(r0.w);
    }
    if (j < deg && half == 0) {    // odd remainder: first half only
        int s0 = csr[start + j];
        float e0 = es1[s0 * 4 + hc] + edv2;
        uint4 r0 = *(const uint4*)&h1[(size_t)s0 * 256 + ch];
        e0 = (e0 > 0.f) ? e0 : 0.2f * e0;
        float p0 = __expf(e0 - mH);
        dn += p0;
        a[0] += p0 * bf_lo(r0.x); a[1] += p0 * bf_hi(r0.x);
        a[2] += p0 * bf_lo(r0.y); a[3] += p0 * bf_hi(r0.y);
        a[4] += p0 * bf_lo(r0.z); a[5] += p0 * bf_hi(r0.z);
        a[6] += p0 * bf_lo(r0.w); a[7] += p0 * bf_hi(r0.w);
    }
    // combine halves
    dn += __shfl_xor(dn, 32);
#pragma unroll
    for (int k = 0; k < 8; ++k) a[k] += __shfl_xor(a[k], 32);
    float inv = 1.f / dn;
    // each half stores a disjoint float4: half0 -> ch..ch+3, half1 -> ch+4..ch+7
    int c = ch + half * 4;
    int ao = half * 4;
    float4 bv = *(const float4*)&b1[c];
    float4 gv = *(const float4*)&g1[c];
    float4 ev = *(const float4*)&be1[c];
    float4 mv = *(const float4*)&m1[c];
    float4 vv = *(const float4*)&v1[c];
    float o0 = a[ao + 0] * inv + bv.x, o1 = a[ao + 1] * inv + bv.y;
    float o2 = a[ao + 2] * inv + bv.z, o3 = a[ao + 3] * inv + bv.w;
    o0 = (o0 - mv.x) * rsqrtf(vv.x + EPS_BN) * gv.x + ev.x;
    o1 = (o1 - mv.y) * rsqrtf(vv.y + EPS_BN) * gv.y + ev.y;
    o2 = (o2 - mv.z) * rsqrtf(vv.z + EPS_BN) * gv.z + ev.z;
    o3 = (o3 - mv.w) * rsqrtf(vv.w + EPS_BN) * gv.w + ev.w;
    o0 = (o0 > 0.f) ? o0 : expm1f(o0);
    o1 = (o1 > 0.f) ? o1 : expm1f(o1);
    o2 = (o2 > 0.f) ? o2 : expm1f(o2);
    o3 = (o3 > 0.f) ? o3 : expm1f(o3);
    *(float4*)&hb[(size_t)d * 256 + c] = make_float4(o0, o1, o2, o3);
}

// ---------------- GEMM2: h2(bf16) = hb @ W2, scores es2/ed2 ----------------

#define W2PAD 260

__global__ __launch_bounds__(256, 2)
void k_gemm2(const float* __restrict__ hb, const float* __restrict__ W2,
             const float* __restrict__ a_s, const float* __restrict__ a_d,
             unsigned short* __restrict__ h2, float* __restrict__ es2, float* __restrict__ ed2) {
    __shared__ float w2t[64 * W2PAD];   // [col][k] padded
    __shared__ float xs[8][256];
    __shared__ float asl[64], adl[64];
    int t = threadIdx.x;
    for (int i = t; i < 256 * 64; i += 256) {
        int k = i >> 6, c = i & 63;
        w2t[c * W2PAD + k] = W2[i];
    }
    if (t < 64) { asl[t] = a_s[t]; adl[t] = a_d[t]; }
    int wave = t >> 6, lane = t & 63;
    for (int base = blockIdx.x * 8; base < N_NODES; base += gridDim.x * 8) {
        __syncthreads();
        for (int j = 0; j < 8; ++j) {
            int id = t + j * 256;
            int nd = id >> 8, k = id & 255;
            int node = base + nd;
            xs[nd][k] = (node < N_NODES) ? hb[(size_t)node * 256 + k] : 0.f;
        }
        __syncthreads();
        int n0 = wave * 2;
        float acc0 = 0.f, acc1 = 0.f;
#pragma unroll 4
        for (int kg = 0; kg < 64; ++kg) {
            float4 wv = *(const float4*)&w2t[lane * W2PAD + kg * 4];
            float4 x0 = *(const float4*)&xs[n0][kg * 4];
            float4 x1 = *(const float4*)&xs[n0 + 1][kg * 4];
            acc0 += wv.x * x0.x + wv.y * x0.y + wv.z * x0.z + wv.w * x0.w;
            acc1 += wv.x * x1.x + wv.y * x1.y + wv.z * x1.z + wv.w * x1.w;
        }
        float pa0 = acc0 * asl[lane], pd0 = acc0 * adl[lane];
        float pa1 = acc1 * asl[lane], pd1 = acc1 * adl[lane];
#pragma unroll
        for (int m = 1; m <= 32; m <<= 1) {
            pa0 += __shfl_xor(pa0, m); pd0 += __shfl_xor(pd0, m);
            pa1 += __shfl_xor(pa1, m); pd1 += __shfl_xor(pd1, m);
        }
        int node0 = base + n0, node1 = node0 + 1;
        if (node0 < N_NODES) {
            h2[(size_t)node0 * 64 + lane] = f2bf(acc0);
            if (lane == 0) { es2[node0] = pa0; ed2[node0] = pd0; }
        }
        if (node1 < N_NODES) {
            h2[(size_t)node1 * 64 + lane] = f2bf(acc1);
            if (lane == 0) { es2[node1] = pa1; ed2[node1] = pd1; }
        }
    }
}

// ---------------- GAT2 aggregate + bias + BN ----------------
// wave per dst node (4/block); half-wave covers a 64-ch row (uint = 2 bf16/lane),
// 2 edges per iteration, ×2 unrolled.

__global__ __launch_bounds__(256)
void k_gat2(const unsigned short* __restrict__ h2, const float* __restrict__ es2,
            const float* __restrict__ ed2, const int* __restrict__ offs,
            const int* __restrict__ csr, const float* __restrict__ b2,
            const float* __restrict__ g2, const float* __restrict__ be2,
            const float* __restrict__ m2, const float* __restrict__ v2,
            float* __restrict__ out2) {
    int wave = threadIdx.x >> 6, lane = threadIdx.x & 63;
    int d = blockIdx.x * 4 + wave;
    if (d >= N_NODES) return;
    int start = offs[d], deg = offs[d + 1] - start;
    float edv = ed2[d];
    float mx = -1e30f;
    for (int j = lane; j < deg; j += 64) {
        int s = csr[start + j];
        float e = es2[s] + edv;
        e = (e > 0.f) ? e : 0.2f * e;
        mx = fmaxf(mx, e);
    }
#pragma unroll
    for (int m = 1; m <= 32; m <<= 1) mx = fmaxf(mx, __shfl_xor(mx, m));
    int half = lane >> 5;
    int cg = lane & 31;
    int ch = cg * 2;
    float a0 = 0.f, a1 = 0.f, dn = 0.f;
    int j = 0;
    for (; j + 4 <= deg; j += 4) {
        int s0 = csr[start + j + half];
        int s1 = csr[start + j + 2 + half];
        float e0 = es2[s0] + edv;
        float e1 = es2[s1] + edv;
        unsigned r0 = *(const unsigned*)&h2[(size_t)s0 * 64 + ch];
        unsigned r1 = *(const unsigned*)&h2[(size_t)s1 * 64 + ch];
        e0 = (e0 > 0.f) ? e0 : 0.2f * e0;
        e1 = (e1 > 0.f) ? e1 : 0.2f * e1;
        float p0 = __expf(e0 - mx);
        float p1 = __expf(e1 - mx);
        dn += p0 + p1;
        a0 += p0 * bf_lo(r0); a1 += p0 * bf_hi(r0);
        a0 += p1 * bf_lo(r1); a1 += p1 * bf_hi(r1);
    }
    for (; j + 2 <= deg; j += 2) {
        int s0 = csr[start + j + half];
        float e0 = es2[s0] + edv;
        unsigned r0 = *(const unsigned*)&h2[(size_t)s0 * 64 + ch];
        e0 = (e0 > 0.f) ? e0 : 0.2f * e0;
        float p0 = __expf(e0 - mx);
        dn += p0;
        a0 += p0 * bf_lo(r0); a1 += p0 * bf_hi(r0);
    }
    if (j < deg && half == 0) {
        int s0 = csr[start + j];
        float e0 = es2[s0] + edv;
        unsigned r0 = *(const unsigned*)&h2[(size_t)s0 * 64 + ch];
        e0 = (e0 > 0.f) ? e0 : 0.2f * e0;
        float p0 = __expf(e0 - mx);
        dn += p0;
        a0 += p0 * bf_lo(r0); a1 += p0 * bf_hi(r0);
    }
    dn += __shfl_xor(dn, 32);
    a0 += __shfl_xor(a0, 32);
    a1 += __shfl_xor(a1, 32);
    if (half == 0) {
        float inv = 1.f / dn;
        float o0 = a0 * inv + b2[ch];
        float o1 = a1 * inv + b2[ch + 1];
        o0 = (o0 - m2[ch]) * rsqrtf(v2[ch] + EPS_BN) * g2[ch] + be2[ch];
        o1 = (o1 - m2[ch + 1]) * rsqrtf(v2[ch + 1] + EPS_BN) * g2[ch + 1] + be2[ch + 1];
        *(float2*)&out2[(size_t)d * 64 + ch] = make_float2(o0, o1);
    }
}

// ---------------- mean pool per graph ----------------

__device__ int lower_bound_i(const int* a, int n, int key) {
    int lo = 0, hi = n;
    while (lo < hi) {
        int mid = (lo + hi) >> 1;
        if (a[mid] < key) lo = mid + 1; else hi = mid;
    }
    return lo;
}

__global__ __launch_bounds__(256)
void k_pool(const float* __restrict__ out2, const int* __restrict__ batch,
            float* __restrict__ pooled) {
    int g = blockIdx.x;
    __shared__ int ssh[2];
    __shared__ float red[256];
    if (threadIdx.x == 0) {
        ssh[0] = lower_bound_i(batch, N_NODES, g);
        ssh[1] = lower_bound_i(batch, N_NODES, g + 1);
    }
    __syncthreads();
    int start = ssh[0], end = ssh[1];
    int t = threadIdx.x, sub = t >> 6, lane = t & 63;
    float acc = 0.f;
    for (int i = start + sub; i < end; i += 4) acc += out2[(size_t)i * 64 + lane];
    red[t] = acc; __syncthreads();
    if (t < 64) {
        float s = red[t] + red[t + 64] + red[t + 128] + red[t + 192];
        int cnt = end - start;
        pooled[g * 64 + t] = s / (float)((cnt > 0) ? cnt : 1);
    }
}

// ---------------- MLP head + log_softmax ----------------

__global__ void k_head(const float* __restrict__ pooled, const float* __restrict__ lw1,
                       const float* __restrict__ lb1, const float* __restrict__ lw2,
                       const float* __restrict__ lb2, float* __restrict__ out) {
    int g = threadIdx.x;
    if (g >= GGRAPHS) return;
    float p[64];
#pragma unroll
    for (int c = 0; c < 64; ++c) p[c] = pooled[g * 64 + c];
    float z0 = lb2[0], z1 = lb2[1], z2 = lb2[2];
    for (int j = 0; j < 32; ++j) {
        float hj = lb1[j];
#pragma unroll
        for (int c = 0; c < 64; ++c) hj += p[c] * lw1[c * 32 + j];
        hj = fmaxf(hj, 0.f);
        z0 += hj * lw2[j * 3 + 0];
        z1 += hj * lw2[j * 3 + 1];
        z2 += hj * lw2[j * 3 + 2];
    }
    float m = fmaxf(z0, fmaxf(z1, z2));
    float lse = logf(expf(z0 - m) + expf(z1 - m) + expf(z2 - m)) + m;
    out[g * 3 + 0] = z0 - lse;
    out[g * 3 + 1] = z1 - lse;
    out[g * 3 + 2] = z2 - lse;
}

// ---------------- launch ----------------

extern "C" void kernel_launch(void* const* d_in, const int* in_sizes, int n_in,
                              void* d_out, int out_size, void* d_ws, size_t ws_size,
                              hipStream_t stream) {
    (void)in_sizes; (void)n_in; (void)out_size; (void)ws_size;
    const float* x    = (const float*)d_in[0];
    const int*   ei   = (const int*)d_in[1];
    const int*   batch= (const int*)d_in[2];
    const float* W1   = (const float*)d_in[3];
    const float* a_s1 = (const float*)d_in[4];
    const float* a_d1 = (const float*)d_in[5];
    const float* b1   = (const float*)d_in[6];
    const float* g1   = (const float*)d_in[7];
    const float* be1  = (const float*)d_in[8];
    const float* m1   = (const float*)d_in[9];
    const float* v1   = (const float*)d_in[10];
    const float* W2   = (const float*)d_in[11];
    const float* a_s2 = (const float*)d_in[12];
    const float* a_d2 = (const float*)d_in[13];
    const float* b2   = (const float*)d_in[14];
    const float* g2   = (const float*)d_in[15];
    const float* be2  = (const float*)d_in[16];
    const float* m2   = (const float*)d_in[17];
    const float* v2   = (const float*)d_in[18];
    const float* lw1  = (const float*)d_in[19];
    const float* lb1  = (const float*)d_in[20];
    const float* lw2  = (const float*)d_in[21];
    const float* lb2  = (const float*)d_in[22];
    float* out = (float*)d_out;

    char* ws = (char*)d_ws;
    size_t off = 0;
    auto alloc = [&](size_t bytes) -> void* {
        void* p = ws + off;
        off += (bytes + 255) & ~(size_t)255;
        return p;
    };
    unsigned short* h1 = (unsigned short*)alloc((size_t)N_NODES * 256 * 2);  // bf16
    float* hb   = (float*)alloc((size_t)N_NODES * 256 * 4);
    unsigned short* h2 = (unsigned short*)alloc((size_t)N_NODES * 64 * 2);   // bf16
    float* out2 = (float*)alloc((size_t)N_NODES * 64 * 4);
    float* es1  = (float*)alloc((size_t)N_NODES * 4 * 4);
    float* ed1  = (float*)alloc((size_t)N_NODES * 4 * 4);
    float* es2  = (float*)alloc((size_t)N_NODES * 4);
    float* ed2  = (float*)alloc((size_t)N_NODES * 4);
    float* pooled = (float*)alloc((size_t)GGRAPHS * 64 * 4);
    int*   cnt  = (int*)alloc((size_t)N_NODES * 4);
    int*   offs = (int*)alloc((size_t)(N_NODES + 1) * 4);
    int*   curs = (int*)alloc((size_t)N_NODES * 4);
    int*   csr  = (int*)alloc((size_t)ETOT * 4);
    int*   bsums= (int*)alloc(256 * 4);

    const int nscan = (N_NODES + 255) / 256;   // 196
    const int nedge = (ETOT + 255) / 256;      // 3321

    hipMemsetAsync(cnt, 0, (size_t)N_NODES * 4, stream);
    k_hist<<<nedge, 256, 0, stream>>>(ei, cnt);
    k_scan_local<<<nscan, 256, 0, stream>>>(cnt, offs, bsums);
    k_scan_sums<<<1, 256, 0, stream>>>(bsums, nscan);
    k_scan_add<<<nscan, 256, 0, stream>>>(offs, curs, bsums);
    k_fill<<<nedge, 256, 0, stream>>>(ei, curs, csr);

    k_gemm1<<<512, 256, 0, stream>>>(x, W1, a_s1, a_d1, h1, es1, ed1);
    k_gat1<<<(N_NODES + 3) / 4, 256, 0, stream>>>(h1, es1, ed1, offs, csr, b1, g1, be1, m1, v1, hb);
    k_gemm2<<<512, 256, 0, stream>>>(hb, W2, a_s2, a_d2, h2, es2, ed2);
    k_gat2<<<(N_NODES + 3) / 4, 256, 0, stream>>>(h2, es2, ed2, offs, csr, b2, g2, be2, m2, v2, out2);
    k_pool<<<GGRAPHS, 256, 0, stream>>>(out2, batch, pooled);
    k_head<<<1, 64, 0, stream>>>(pooled, lw1, lb1, lw2, lb2, out);
}

// Round 4
// 413.818 us; speedup vs baseline: 1.7117x; 1.2275x over previous
//
#include <hip/hip_runtime.h>
#include <math.h>

#define N_NODES 50000
#define N_EDGES 800000
#define ETOT    (N_EDGES + N_NODES)   // self-loops appended
#define GGRAPHS 64
#define EPS_BN  1e-5f

typedef __attribute__((ext_vector_type(8))) short short8;
typedef __attribute__((ext_vector_type(4))) float f32x4;

__device__ __forceinline__ unsigned short f2bf(float f) {
    union { float f; unsigned u; } v; v.f = f;
    unsigned r = v.u + 0x7fffu + ((v.u >> 16) & 1u);   // round-nearest-even
    return (unsigned short)(r >> 16);
}
__device__ __forceinline__ float bf_lo(unsigned u) {
    union { unsigned u; float f; } v; v.u = u << 16; return v.f;
}
__device__ __forceinline__ float bf_hi(unsigned u) {
    union { unsigned u; float f; } v; v.u = u & 0xffff0000u; return v.f;
}

// ---------------- CSR build ----------------

__global__ void k_hist(const int* __restrict__ ei, int* __restrict__ cnt) {
    int e = blockIdx.x * 256 + threadIdx.x;
    if (e >= ETOT) return;
    int d = (e < N_EDGES) ? ei[N_EDGES + e] : (e - N_EDGES);
    atomicAdd(&cnt[d], 1);
}

__global__ void k_scan_local(const int* __restrict__ cnt, int* __restrict__ offs,
                             int* __restrict__ bsums) {
    __shared__ int s[256];
    int t = threadIdx.x, idx = blockIdx.x * 256 + t;
    int v = (idx < N_NODES) ? cnt[idx] : 0;
    s[t] = v; __syncthreads();
    for (int d2 = 1; d2 < 256; d2 <<= 1) {
        int add = (t >= d2) ? s[t - d2] : 0;
        __syncthreads();
        s[t] += add;
        __syncthreads();
    }
    if (idx < N_NODES) offs[idx] = s[t] - v;       // local exclusive
    if (t == 255) bsums[blockIdx.x] = s[255];
}

__global__ void k_scan_sums(int* __restrict__ bsums, int nb) {
    __shared__ int s[256];
    int t = threadIdx.x;
    int v = (t < nb) ? bsums[t] : 0;
    s[t] = v; __syncthreads();
    for (int d2 = 1; d2 < 256; d2 <<= 1) {
        int add = (t >= d2) ? s[t - d2] : 0;
        __syncthreads();
        s[t] += add;
        __syncthreads();
    }
    if (t < nb) bsums[t] = s[t] - v;               // exclusive
}

__global__ void k_scan_add(int* __restrict__ offs, int* __restrict__ cursor,
                           const int* __restrict__ bsums) {
    int idx = blockIdx.x * 256 + threadIdx.x;
    if (idx < N_NODES) {
        int o = offs[idx] + bsums[blockIdx.x];
        offs[idx] = o;
        cursor[idx] = o;
    }
    if (idx == 0) offs[N_NODES] = ETOT;
}

__global__ void k_fill(const int* __restrict__ ei, int* __restrict__ cursor,
                       int* __restrict__ csr) {
    int e = blockIdx.x * 256 + threadIdx.x;
    if (e >= ETOT) return;
    int s, d;
    if (e < N_EDGES) { s = ei[e]; d = ei[N_EDGES + e]; }
    else             { s = d = e - N_EDGES; }
    int pos = atomicAdd(&cursor[d], 1);
    csr[pos] = s;
}

// ---------------- x -> bf16 convert ----------------

__global__ void k_xbf(const float* __restrict__ x, unsigned short* __restrict__ xbf) {
    int i = blockIdx.x * 256 + threadIdx.x;          // quad index
    if (i * 4 >= N_NODES * 64) return;
    float4 v = *(const float4*)&x[i * 4];
    ushort4 o;
    o.x = f2bf(v.x); o.y = f2bf(v.y); o.z = f2bf(v.z); o.w = f2bf(v.w);
    *(ushort4*)&xbf[i * 4] = o;
}

// ---------------- GEMM1 (MFMA): h1(bf16) = x @ W1, scores es1/ed1 ----------------
// wave-tile = 16 nodes; A from global (x_bf rows), B = W1^T in LDS [n][k] pad 72.
// N=256 -> 16 ntiles, K=64 -> 2 mfma steps per ntile.

__global__ __launch_bounds__(256)
void k_gemm1(const unsigned short* __restrict__ xbf, const float* __restrict__ W1,
             const float* __restrict__ a_s, const float* __restrict__ a_d,
             unsigned short* __restrict__ h1, float* __restrict__ es1, float* __restrict__ ed1) {
    __shared__ unsigned short W1T[256 * 72];
    int t = threadIdx.x;
    for (int i = t; i < 64 * 256; i += 256) {
        int k = i >> 8, n = i & 255;
        W1T[n * 72 + k] = f2bf(W1[i]);               // W1[k*256+n]
    }
    __syncthreads();
    int wid = t >> 6, lane = t & 63;
    int quad = lane >> 4, col = lane & 15;
    float as_r[16], ad_r[16];
#pragma unroll
    for (int i = 0; i < 16; ++i) {
        as_r[i] = a_s[i * 16 + col];                 // a_s[head][ (nt&3)*16+col ] flattened
        ad_r[i] = a_d[i * 16 + col];
    }
    int tile = blockIdx.x * 4 + wid;
    if (tile >= 3125) return;
    int base = tile * 16;
    short8 a0 = *(const short8*)&xbf[(size_t)(base + col) * 64 + quad * 8];
    short8 a1 = *(const short8*)&xbf[(size_t)(base + col) * 64 + 32 + quad * 8];
    f32x4 acc[16];
#pragma unroll
    for (int nt = 0; nt < 16; ++nt) acc[nt] = (f32x4){0.f, 0.f, 0.f, 0.f};
#pragma unroll
    for (int nt = 0; nt < 16; ++nt) {
        short8 b0 = *(const short8*)&W1T[(nt * 16 + col) * 72 + quad * 8];
        short8 b1 = *(const short8*)&W1T[(nt * 16 + col) * 72 + 32 + quad * 8];
        acc[nt] = __builtin_amdgcn_mfma_f32_16x16x32_bf16(a0, b0, acc[nt], 0, 0, 0);
        acc[nt] = __builtin_amdgcn_mfma_f32_16x16x32_bf16(a1, b1, acc[nt], 0, 0, 0);
    }
    // scores: esp[hd*4+r] = sum over 64 head channels
    float esp[16], edp[16];
#pragma unroll
    for (int i = 0; i < 16; ++i) { esp[i] = 0.f; edp[i] = 0.f; }
#pragma unroll
    for (int nt = 0; nt < 16; ++nt) {
        int hd = nt >> 2;
#pragma unroll
        for (int r = 0; r < 4; ++r) {
            esp[hd * 4 + r] += acc[nt][r] * as_r[nt];
            edp[hd * 4 + r] += acc[nt][r] * ad_r[nt];
        }
    }
#pragma unroll
    for (int i = 0; i < 16; ++i) {
        float v = esp[i], w = edp[i];
#pragma unroll
        for (int m = 1; m <= 8; m <<= 1) { v += __shfl_xor(v, m); w += __shfl_xor(w, m); }
        esp[i] = v; edp[i] = w;
    }
    if (col == 0) {
#pragma unroll
        for (int hd = 0; hd < 4; ++hd)
#pragma unroll
            for (int r = 0; r < 4; ++r) {
                int node = base + quad * 4 + r;
                es1[node * 4 + hd] = esp[hd * 4 + r];
                ed1[node * 4 + hd] = edp[hd * 4 + r];
            }
    }
    // h1 store (bf16)
#pragma unroll
    for (int nt = 0; nt < 16; ++nt)
#pragma unroll
        for (int r = 0; r < 4; ++r)
            h1[(size_t)(base + quad * 4 + r) * 256 + nt * 16 + col] = f2bf(acc[nt][r]);
}

// ---------------- GAT1 aggregate + bias + BN + ELU -> hb(bf16) ----------------
// wave per dst node (4/block). Phase 2: half-wave covers a 256-ch row
// (uint4 = 8 bf16/lane), 2 edges per iteration, ×2 unrolled (4 in flight).

__global__ __launch_bounds__(256)
void k_gat1(const unsigned short* __restrict__ h1, const float* __restrict__ es1,
            const float* __restrict__ ed1, const int* __restrict__ offs,
            const int* __restrict__ csr, const float* __restrict__ b1,
            const float* __restrict__ g1, const float* __restrict__ be1,
            const float* __restrict__ m1, const float* __restrict__ v1,
            unsigned short* __restrict__ hb) {
    int wave = threadIdx.x >> 6, lane = threadIdx.x & 63;
    int d = blockIdx.x * 4 + wave;
    if (d >= N_NODES) return;
    int start = offs[d], deg = offs[d + 1] - start;
    int hp = lane & 3;
    float edv = ed1[d * 4 + hp];
    float mx = -1e30f;
    for (int j = lane >> 2; j < deg; j += 16) {
        int s = csr[start + j];
        float e = es1[s * 4 + hp] + edv;
        e = (e > 0.f) ? e : 0.2f * e;
        mx = fmaxf(mx, e);
    }
#pragma unroll
    for (int m = 4; m <= 32; m <<= 1) mx = fmaxf(mx, __shfl_xor(mx, m));
    int half = lane >> 5;
    int cg = lane & 31;
    int ch = cg * 8;
    int hc = cg >> 3;
    float mH = __shfl(mx, hc);
    float edv2 = ed1[d * 4 + hc];
    float a[8];
#pragma unroll
    for (int k = 0; k < 8; ++k) a[k] = 0.f;
    float dn = 0.f;
    int j = 0;
    for (; j + 4 <= deg; j += 4) {
        int s0 = csr[start + j + half];
        int s1 = csr[start + j + 2 + half];
        float e0 = es1[s0 * 4 + hc] + edv2;
        float e1 = es1[s1 * 4 + hc] + edv2;
        uint4 r0 = *(const uint4*)&h1[(size_t)s0 * 256 + ch];
        uint4 r1 = *(const uint4*)&h1[(size_t)s1 * 256 + ch];
        e0 = (e0 > 0.f) ? e0 : 0.2f * e0;
        e1 = (e1 > 0.f) ? e1 : 0.2f * e1;
        float p0 = __expf(e0 - mH);
        float p1 = __expf(e1 - mH);
        dn += p0 + p1;
        a[0] += p0 * bf_lo(r0.x); a[1] += p0 * bf_hi(r0.x);
        a[2] += p0 * bf_lo(r0.y); a[3] += p0 * bf_hi(r0.y);
        a[4] += p0 * bf_lo(r0.z); a[5] += p0 * bf_hi(r0.z);
        a[6] += p0 * bf_lo(r0.w); a[7] += p0 * bf_hi(r0.w);
        a[0] += p1 * bf_lo(r1.x); a[1] += p1 * bf_hi(r1.x);
        a[2] += p1 * bf_lo(r1.y); a[3] += p1 * bf_hi(r1.y);
        a[4] += p1 * bf_lo(r1.z); a[5] += p1 * bf_hi(r1.z);
        a[6] += p1 * bf_lo(r1.w); a[7] += p1 * bf_hi(r1.w);
    }
    for (; j + 2 <= deg; j += 2) {
        int s0 = csr[start + j + half];
        float e0 = es1[s0 * 4 + hc] + edv2;
        uint4 r0 = *(const uint4*)&h1[(size_t)s0 * 256 + ch];
        e0 = (e0 > 0.f) ? e0 : 0.2f * e0;
        float p0 = __expf(e0 - mH);
        dn += p0;
        a[0] += p0 * bf_lo(r0.x); a[1] += p0 * bf_hi(r0.x);
        a[2] += p0 * bf_lo(r0.y); a[3] += p0 * bf_hi(r0.y);
        a[4] += p0 * bf_lo(r0.z); a[5] += p0 * bf_hi(r0.z);
        a[6] += p0 * bf_lo(r0.w); a[7] += p0 * bf_hi(r0.w);
    }
    if (j < deg && half == 0) {
        int s0 = csr[start + j];
        float e0 = es1[s0 * 4 + hc] + edv2;
        uint4 r0 = *(const uint4*)&h1[(size_t)s0 * 256 + ch];
        e0 = (e0 > 0.f) ? e0 : 0.2f * e0;
        float p0 = __expf(e0 - mH);
        dn += p0;
        a[0] += p0 * bf_lo(r0.x); a[1] += p0 * bf_hi(r0.x);
        a[2] += p0 * bf_lo(r0.y); a[3] += p0 * bf_hi(r0.y);
        a[4] += p0 * bf_lo(r0.z); a[5] += p0 * bf_hi(r0.z);
        a[6] += p0 * bf_lo(r0.w); a[7] += p0 * bf_hi(r0.w);
    }
    dn += __shfl_xor(dn, 32);
#pragma unroll
    for (int k = 0; k < 8; ++k) a[k] += __shfl_xor(a[k], 32);
    float inv = 1.f / dn;
    int c = ch + half * 4;
    int ao = half * 4;
    float4 bv = *(const float4*)&b1[c];
    float4 gv = *(const float4*)&g1[c];
    float4 ev = *(const float4*)&be1[c];
    float4 mv = *(const float4*)&m1[c];
    float4 vv = *(const float4*)&v1[c];
    float o0 = a[ao + 0] * inv + bv.x, o1 = a[ao + 1] * inv + bv.y;
    float o2 = a[ao + 2] * inv + bv.z, o3 = a[ao + 3] * inv + bv.w;
    o0 = (o0 - mv.x) * rsqrtf(vv.x + EPS_BN) * gv.x + ev.x;
    o1 = (o1 - mv.y) * rsqrtf(vv.y + EPS_BN) * gv.y + ev.y;
    o2 = (o2 - mv.z) * rsqrtf(vv.z + EPS_BN) * gv.z + ev.z;
    o3 = (o3 - mv.w) * rsqrtf(vv.w + EPS_BN) * gv.w + ev.w;
    o0 = (o0 > 0.f) ? o0 : expm1f(o0);
    o1 = (o1 > 0.f) ? o1 : expm1f(o1);
    o2 = (o2 > 0.f) ? o2 : expm1f(o2);
    o3 = (o3 > 0.f) ? o3 : expm1f(o3);
    ushort4 ov;
    ov.x = f2bf(o0); ov.y = f2bf(o1); ov.z = f2bf(o2); ov.w = f2bf(o3);
    *(ushort4*)&hb[(size_t)d * 256 + c] = ov;
}

// ---------------- GEMM2 (MFMA): h2(bf16) = hb @ W2, scores es2/ed2 ----------------
// wave-tile = 16 nodes; A = hb rows (8 prefetched frags), B = W2^T LDS [n][k] pad 264.
// N=64 -> 4 ntiles, K=256 -> 8 mfma steps per ntile.

__global__ __launch_bounds__(256)
void k_gemm2(const unsigned short* __restrict__ hbbf, const float* __restrict__ W2,
             const float* __restrict__ a_s, const float* __restrict__ a_d,
             unsigned short* __restrict__ h2, float* __restrict__ es2, float* __restrict__ ed2) {
    __shared__ unsigned short W2T[64 * 264];
    int t = threadIdx.x;
    for (int i = t; i < 256 * 64; i += 256) {
        int k = i >> 6, n = i & 63;
        W2T[n * 264 + k] = f2bf(W2[i]);              // W2[k*64+n]
    }
    __syncthreads();
    int wid = t >> 6, lane = t & 63;
    int quad = lane >> 4, col = lane & 15;
    float as_r[4], ad_r[4];
#pragma unroll
    for (int i = 0; i < 4; ++i) {
        as_r[i] = a_s[i * 16 + col];
        ad_r[i] = a_d[i * 16 + col];
    }
    int tile = blockIdx.x * 4 + wid;
    if (tile >= 3125) return;
    int base = tile * 16;
    short8 af[8];
#pragma unroll
    for (int kk = 0; kk < 8; ++kk)
        af[kk] = *(const short8*)&hbbf[(size_t)(base + col) * 256 + kk * 32 + quad * 8];
    f32x4 acc[4];
#pragma unroll
    for (int nt = 0; nt < 4; ++nt) acc[nt] = (f32x4){0.f, 0.f, 0.f, 0.f};
#pragma unroll
    for (int kk = 0; kk < 8; ++kk) {
#pragma unroll
        for (int nt = 0; nt < 4; ++nt) {
            short8 b = *(const short8*)&W2T[(nt * 16 + col) * 264 + kk * 32 + quad * 8];
            acc[nt] = __builtin_amdgcn_mfma_f32_16x16x32_bf16(af[kk], b, acc[nt], 0, 0, 0);
        }
    }
    float esp[4], edp[4];
#pragma unroll
    for (int r = 0; r < 4; ++r) { esp[r] = 0.f; edp[r] = 0.f; }
#pragma unroll
    for (int nt = 0; nt < 4; ++nt)
#pragma unroll
        for (int r = 0; r < 4; ++r) {
            esp[r] += acc[nt][r] * as_r[nt];
            edp[r] += acc[nt][r] * ad_r[nt];
        }
#pragma unroll
    for (int r = 0; r < 4; ++r) {
        float v = esp[r], w = edp[r];
#pragma unroll
        for (int m = 1; m <= 8; m <<= 1) { v += __shfl_xor(v, m); w += __shfl_xor(w, m); }
        esp[r] = v; edp[r] = w;
    }
    if (col == 0) {
#pragma unroll
        for (int r = 0; r < 4; ++r) {
            int node = base + quad * 4 + r;
            es2[node] = esp[r];
            ed2[node] = edp[r];
        }
    }
#pragma unroll
    for (int nt = 0; nt < 4; ++nt)
#pragma unroll
        for (int r = 0; r < 4; ++r)
            h2[(size_t)(base + quad * 4 + r) * 64 + nt * 16 + col] = f2bf(acc[nt][r]);
}

// ---------------- GAT2 aggregate + bias + BN ----------------
// wave per dst node (4/block); half-wave covers a 64-ch row (uint = 2 bf16/lane),
// 2 edges per iteration, ×2 unrolled.

__global__ __launch_bounds__(256)
void k_gat2(const unsigned short* __restrict__ h2, const float* __restrict__ es2,
            const float* __restrict__ ed2, const int* __restrict__ offs,
            const int* __restrict__ csr, const float* __restrict__ b2,
            const float* __restrict__ g2, const float* __restrict__ be2,
            const float* __restrict__ m2, const float* __restrict__ v2,
            float* __restrict__ out2) {
    int wave = threadIdx.x >> 6, lane = threadIdx.x & 63;
    int d = blockIdx.x * 4 + wave;
    if (d >= N_NODES) return;
    int start = offs[d], deg = offs[d + 1] - start;
    float edv = ed2[d];
    float mx = -1e30f;
    for (int j = lane; j < deg; j += 64) {
        int s = csr[start + j];
        float e = es2[s] + edv;
        e = (e > 0.f) ? e : 0.2f * e;
        mx = fmaxf(mx, e);
    }
#pragma unroll
    for (int m = 1; m <= 32; m <<= 1) mx = fmaxf(mx, __shfl_xor(mx, m));
    int half = lane >> 5;
    int cg = lane & 31;
    int ch = cg * 2;
    float a0 = 0.f, a1 = 0.f, dn = 0.f;
    int j = 0;
    for (; j + 4 <= deg; j += 4) {
        int s0 = csr[start + j + half];
        int s1 = csr[start + j + 2 + half];
        float e0 = es2[s0] + edv;
        float e1 = es2[s1] + edv;
        unsigned r0 = *(const unsigned*)&h2[(size_t)s0 * 64 + ch];
        unsigned r1 = *(const unsigned*)&h2[(size_t)s1 * 64 + ch];
        e0 = (e0 > 0.f) ? e0 : 0.2f * e0;
        e1 = (e1 > 0.f) ? e1 : 0.2f * e1;
        float p0 = __expf(e0 - mx);
        float p1 = __expf(e1 - mx);
        dn += p0 + p1;
        a0 += p0 * bf_lo(r0); a1 += p0 * bf_hi(r0);
        a0 += p1 * bf_lo(r1); a1 += p1 * bf_hi(r1);
    }
    for (; j + 2 <= deg; j += 2) {
        int s0 = csr[start + j + half];
        float e0 = es2[s0] + edv;
        unsigned r0 = *(const unsigned*)&h2[(size_t)s0 * 64 + ch];
        e0 = (e0 > 0.f) ? e0 : 0.2f * e0;
        float p0 = __expf(e0 - mx);
        dn += p0;
        a0 += p0 * bf_lo(r0); a1 += p0 * bf_hi(r0);
    }
    if (j < deg && half == 0) {
        int s0 = csr[start + j];
        float e0 = es2[s0] + edv;
        unsigned r0 = *(const unsigned*)&h2[(size_t)s0 * 64 + ch];
        e0 = (e0 > 0.f) ? e0 : 0.2f * e0;
        float p0 = __expf(e0 - mx);
        dn += p0;
        a0 += p0 * bf_lo(r0); a1 += p0 * bf_hi(r0);
    }
    dn += __shfl_xor(dn, 32);
    a0 += __shfl_xor(a0, 32);
    a1 += __shfl_xor(a1, 32);
    if (half == 0) {
        float inv = 1.f / dn;
        float o0 = a0 * inv + b2[ch];
        float o1 = a1 * inv + b2[ch + 1];
        o0 = (o0 - m2[ch]) * rsqrtf(v2[ch] + EPS_BN) * g2[ch] + be2[ch];
        o1 = (o1 - m2[ch + 1]) * rsqrtf(v2[ch + 1] + EPS_BN) * g2[ch + 1] + be2[ch + 1];
        *(float2*)&out2[(size_t)d * 64 + ch] = make_float2(o0, o1);
    }
}

// ---------------- mean pool per graph ----------------

__device__ int lower_bound_i(const int* a, int n, int key) {
    int lo = 0, hi = n;
    while (lo < hi) {
        int mid = (lo + hi) >> 1;
        if (a[mid] < key) lo = mid + 1; else hi = mid;
    }
    return lo;
}

__global__ __launch_bounds__(256)
void k_pool(const float* __restrict__ out2, const int* __restrict__ batch,
            float* __restrict__ pooled) {
    int g = blockIdx.x;
    __shared__ int ssh[2];
    __shared__ float red[256];
    if (threadIdx.x == 0) {
        ssh[0] = lower_bound_i(batch, N_NODES, g);
        ssh[1] = lower_bound_i(batch, N_NODES, g + 1);
    }
    __syncthreads();
    int start = ssh[0], end = ssh[1];
    int t = threadIdx.x, sub = t >> 6, lane = t & 63;
    float acc = 0.f;
    for (int i = start + sub; i < end; i += 4) acc += out2[(size_t)i * 64 + lane];
    red[t] = acc; __syncthreads();
    if (t < 64) {
        float s = red[t] + red[t + 64] + red[t + 128] + red[t + 192];
        int cnt = end - start;
        pooled[g * 64 + t] = s / (float)((cnt > 0) ? cnt : 1);
    }
}

// ---------------- MLP head + log_softmax ----------------

__global__ void k_head(const float* __restrict__ pooled, const float* __restrict__ lw1,
                       const float* __restrict__ lb1, const float* __restrict__ lw2,
                       const float* __restrict__ lb2, float* __restrict__ out) {
    int g = threadIdx.x;
    if (g >= GGRAPHS) return;
    float p[64];
#pragma unroll
    for (int c = 0; c < 64; ++c) p[c] = pooled[g * 64 + c];
    float z0 = lb2[0], z1 = lb2[1], z2 = lb2[2];
    for (int j = 0; j < 32; ++j) {
        float hj = lb1[j];
#pragma unroll
        for (int c = 0; c < 64; ++c) hj += p[c] * lw1[c * 32 + j];
        hj = fmaxf(hj, 0.f);
        z0 += hj * lw2[j * 3 + 0];
        z1 += hj * lw2[j * 3 + 1];
        z2 += hj * lw2[j * 3 + 2];
    }
    float m = fmaxf(z0, fmaxf(z1, z2));
    float lse = logf(expf(z0 - m) + expf(z1 - m) + expf(z2 - m)) + m;
    out[g * 3 + 0] = z0 - lse;
    out[g * 3 + 1] = z1 - lse;
    out[g * 3 + 2] = z2 - lse;
}

// ---------------- launch ----------------

extern "C" void kernel_launch(void* const* d_in, const int* in_sizes, int n_in,
                              void* d_out, int out_size, void* d_ws, size_t ws_size,
                              hipStream_t stream) {
    (void)in_sizes; (void)n_in; (void)out_size; (void)ws_size;
    const float* x    = (const float*)d_in[0];
    const int*   ei   = (const int*)d_in[1];
    const int*   batch= (const int*)d_in[2];
    const float* W1   = (const float*)d_in[3];
    const float* a_s1 = (const float*)d_in[4];
    const float* a_d1 = (const float*)d_in[5];
    const float* b1   = (const float*)d_in[6];
    const float* g1   = (const float*)d_in[7];
    const float* be1  = (const float*)d_in[8];
    const float* m1   = (const float*)d_in[9];
    const float* v1   = (const float*)d_in[10];
    const float* W2   = (const float*)d_in[11];
    const float* a_s2 = (const float*)d_in[12];
    const float* a_d2 = (const float*)d_in[13];
    const float* b2   = (const float*)d_in[14];
    const float* g2   = (const float*)d_in[15];
    const float* be2  = (const float*)d_in[16];
    const float* m2   = (const float*)d_in[17];
    const float* v2   = (const float*)d_in[18];
    const float* lw1  = (const float*)d_in[19];
    const float* lb1  = (const float*)d_in[20];
    const float* lw2  = (const float*)d_in[21];
    const float* lb2  = (const float*)d_in[22];
    float* out = (float*)d_out;

    char* ws = (char*)d_ws;
    size_t off = 0;
    auto alloc = [&](size_t bytes) -> void* {
        void* p = ws + off;
        off += (bytes + 255) & ~(size_t)255;
        return p;
    };
    unsigned short* xbf = (unsigned short*)alloc((size_t)N_NODES * 64 * 2);   // bf16
    unsigned short* h1  = (unsigned short*)alloc((size_t)N_NODES * 256 * 2);  // bf16
    unsigned short* hb  = (unsigned short*)alloc((size_t)N_NODES * 256 * 2);  // bf16
    unsigned short* h2  = (unsigned short*)alloc((size_t)N_NODES * 64 * 2);   // bf16
    float* out2 = (float*)alloc((size_t)N_NODES * 64 * 4);
    float* es1  = (float*)alloc((size_t)N_NODES * 4 * 4);
    float* ed1  = (float*)alloc((size_t)N_NODES * 4 * 4);
    float* es2  = (float*)alloc((size_t)N_NODES * 4);
    float* ed2  = (float*)alloc((size_t)N_NODES * 4);
    float* pooled = (float*)alloc((size_t)GGRAPHS * 64 * 4);
    int*   cnt  = (int*)alloc((size_t)N_NODES * 4);
    int*   offs = (int*)alloc((size_t)(N_NODES + 1) * 4);
    int*   curs = (int*)alloc((size_t)N_NODES * 4);
    int*   csr  = (int*)alloc((size_t)ETOT * 4);
    int*   bsums= (int*)alloc(256 * 4);

    const int nscan = (N_NODES + 255) / 256;   // 196
    const int nedge = (ETOT + 255) / 256;      // 3321
    const int ntileb = (3125 + 3) / 4;         // 782 blocks for MFMA gemms

    hipMemsetAsync(cnt, 0, (size_t)N_NODES * 4, stream);
    k_xbf<<<(N_NODES * 64 / 4 + 255) / 256, 256, 0, stream>>>(x, xbf);
    k_hist<<<nedge, 256, 0, stream>>>(ei, cnt);
    k_scan_local<<<nscan, 256, 0, stream>>>(cnt, offs, bsums);
    k_scan_sums<<<1, 256, 0, stream>>>(bsums, nscan);
    k_scan_add<<<nscan, 256, 0, stream>>>(offs, curs, bsums);
    k_fill<<<nedge, 256, 0, stream>>>(ei, curs, csr);

    k_gemm1<<<ntileb, 256, 0, stream>>>(xbf, W1, a_s1, a_d1, h1, es1, ed1);
    k_gat1<<<(N_NODES + 3) / 4, 256, 0, stream>>>(h1, es1, ed1, offs, csr, b1, g1, be1, m1, v1, hb);
    k_gemm2<<<ntileb, 256, 0, stream>>>(hb, W2, a_s2, a_d2, h2, es2, ed2);
    k_gat2<<<(N_NODES + 3) / 4, 256, 0, stream>>>(h2, es2, ed2, offs, csr, b2, g2, be2, m2, v2, out2);
    k_pool<<<GGRAPHS, 256, 0, stream>>>(out2, batch, pooled);
    k_head<<<1, 64, 0, stream>>>(pooled, lw1, lb1, lw2, lb2, out);
}

// Round 5
// 400.591 us; speedup vs baseline: 1.7682x; 1.0330x over previous
//
#include <hip/hip_runtime.h>
#include <math.h>

#define N_NODES 50000
#define N_EDGES 800000
#define ETOT    (N_EDGES + N_NODES)   // self-loops appended
#define GGRAPHS 64
#define EPS_BN  1e-5f

typedef __attribute__((ext_vector_type(8))) short short8;
typedef __attribute__((ext_vector_type(4))) float f32x4;

__device__ __forceinline__ unsigned short f2bf(float f) {
    union { float f; unsigned u; } v; v.f = f;
    unsigned r = v.u + 0x7fffu + ((v.u >> 16) & 1u);   // round-nearest-even
    return (unsigned short)(r >> 16);
}
__device__ __forceinline__ float bf_lo(unsigned u) {
    union { unsigned u; float f; } v; v.u = u << 16; return v.f;
}
__device__ __forceinline__ float bf_hi(unsigned u) {
    union { unsigned u; float f; } v; v.u = u & 0xffff0000u; return v.f;
}
__device__ __forceinline__ float leaky(float e) {
    return fmaxf(e, 0.2f * e);     // e>0 -> e ; e<0 -> 0.2e
}

// ---------------- CSR build ----------------

__global__ void k_hist(const int* __restrict__ ei, int* __restrict__ cnt) {
    int e = blockIdx.x * 256 + threadIdx.x;
    if (e >= ETOT) return;
    int d = (e < N_EDGES) ? ei[N_EDGES + e] : (e - N_EDGES);
    atomicAdd(&cnt[d], 1);
}

__global__ void k_scan_local(const int* __restrict__ cnt, int* __restrict__ offs,
                             int* __restrict__ bsums) {
    __shared__ int s[256];
    int t = threadIdx.x, idx = blockIdx.x * 256 + t;
    int v = (idx < N_NODES) ? cnt[idx] : 0;
    s[t] = v; __syncthreads();
    for (int d2 = 1; d2 < 256; d2 <<= 1) {
        int add = (t >= d2) ? s[t - d2] : 0;
        __syncthreads();
        s[t] += add;
        __syncthreads();
    }
    if (idx < N_NODES) offs[idx] = s[t] - v;       // local exclusive
    if (t == 255) bsums[blockIdx.x] = s[255];
}

__global__ void k_scan_sums(int* __restrict__ bsums, int nb) {
    __shared__ int s[256];
    int t = threadIdx.x;
    int v = (t < nb) ? bsums[t] : 0;
    s[t] = v; __syncthreads();
    for (int d2 = 1; d2 < 256; d2 <<= 1) {
        int add = (t >= d2) ? s[t - d2] : 0;
        __syncthreads();
        s[t] += add;
        __syncthreads();
    }
    if (t < nb) bsums[t] = s[t] - v;               // exclusive
}

__global__ void k_scan_add(int* __restrict__ offs, int* __restrict__ cursor,
                           const int* __restrict__ bsums) {
    int idx = blockIdx.x * 256 + threadIdx.x;
    if (idx < N_NODES) {
        int o = offs[idx] + bsums[blockIdx.x];
        offs[idx] = o;
        cursor[idx] = o;
    }
    if (idx == 0) offs[N_NODES] = ETOT;
}

__global__ void k_fill(const int* __restrict__ ei, int* __restrict__ cursor,
                       int* __restrict__ csr) {
    int e = blockIdx.x * 256 + threadIdx.x;
    if (e >= ETOT) return;
    int s, d;
    if (e < N_EDGES) { s = ei[e]; d = ei[N_EDGES + e]; }
    else             { s = d = e - N_EDGES; }
    int pos = atomicAdd(&cursor[d], 1);
    csr[pos] = s;
}

// ---------------- prep: x->bf16, W1->W1T bf16 [n][k], W2->W2T bf16 [n][k] ----

#define XQ (N_NODES * 64 / 4)

__global__ void k_prep(const float* __restrict__ x, const float* __restrict__ W1,
                       const float* __restrict__ W2,
                       unsigned short* __restrict__ xbf,
                       unsigned short* __restrict__ W1T,
                       unsigned short* __restrict__ W2T) {
    int t = blockIdx.x * 256 + threadIdx.x;
    if (t < XQ) {
        float4 v = *(const float4*)&x[t * 4];
        ushort4 o;
        o.x = f2bf(v.x); o.y = f2bf(v.y); o.z = f2bf(v.z); o.w = f2bf(v.w);
        *(ushort4*)&xbf[t * 4] = o;
    } else if (t < XQ + 16384) {
        int i = t - XQ;                 // W1T[n*64+k] = W1[k*256+n]
        int n = i >> 6, k = i & 63;
        W1T[i] = f2bf(W1[k * 256 + n]);
    } else if (t < XQ + 32768) {
        int i = t - XQ - 16384;         // W2T[n*256+k] = W2[k*64+n]
        int n = i >> 8, k = i & 255;
        W2T[i] = f2bf(W2[k * 64 + n]);
    }
}

// ---------------- GEMM1 (MFMA): h1(bf16) = x @ W1, scores es1/ed1 ----------------
// wave-tile = 16 nodes; A from global (x_bf rows), B = W1T in LDS [n][k] pad 72.

__global__ __launch_bounds__(256)
void k_gemm1(const unsigned short* __restrict__ xbf, const unsigned short* __restrict__ W1Tg,
             const float* __restrict__ a_s, const float* __restrict__ a_d,
             unsigned short* __restrict__ h1, float* __restrict__ es1, float* __restrict__ ed1) {
    __shared__ unsigned short W1T[256 * 72];
    int t = threadIdx.x;
    for (int c = t; c < 2048; c += 256) {            // 2048 chunks of 8 bf16
        int n = c >> 3, k8 = (c & 7) * 8;
        *(short8*)&W1T[n * 72 + k8] = *(const short8*)&W1Tg[n * 64 + k8];
    }
    __syncthreads();
    int wid = t >> 6, lane = t & 63;
    int quad = lane >> 4, col = lane & 15;
    float as_r[16], ad_r[16];
#pragma unroll
    for (int i = 0; i < 16; ++i) {
        as_r[i] = a_s[i * 16 + col];
        ad_r[i] = a_d[i * 16 + col];
    }
    int tile = blockIdx.x * 4 + wid;
    if (tile >= 3125) return;
    int base = tile * 16;
    short8 a0 = *(const short8*)&xbf[(size_t)(base + col) * 64 + quad * 8];
    short8 a1 = *(const short8*)&xbf[(size_t)(base + col) * 64 + 32 + quad * 8];
    f32x4 acc[16];
#pragma unroll
    for (int nt = 0; nt < 16; ++nt) acc[nt] = (f32x4){0.f, 0.f, 0.f, 0.f};
#pragma unroll
    for (int nt = 0; nt < 16; ++nt) {
        short8 b0 = *(const short8*)&W1T[(nt * 16 + col) * 72 + quad * 8];
        short8 b1 = *(const short8*)&W1T[(nt * 16 + col) * 72 + 32 + quad * 8];
        acc[nt] = __builtin_amdgcn_mfma_f32_16x16x32_bf16(a0, b0, acc[nt], 0, 0, 0);
        acc[nt] = __builtin_amdgcn_mfma_f32_16x16x32_bf16(a1, b1, acc[nt], 0, 0, 0);
    }
    float esp[16], edp[16];
#pragma unroll
    for (int i = 0; i < 16; ++i) { esp[i] = 0.f; edp[i] = 0.f; }
#pragma unroll
    for (int nt = 0; nt < 16; ++nt) {
        int hd = nt >> 2;
#pragma unroll
        for (int r = 0; r < 4; ++r) {
            esp[hd * 4 + r] += acc[nt][r] * as_r[nt];
            edp[hd * 4 + r] += acc[nt][r] * ad_r[nt];
        }
    }
#pragma unroll
    for (int i = 0; i < 16; ++i) {
        float v = esp[i], w = edp[i];
#pragma unroll
        for (int m = 1; m <= 8; m <<= 1) { v += __shfl_xor(v, m); w += __shfl_xor(w, m); }
        esp[i] = v; edp[i] = w;
    }
    if (col == 0) {
#pragma unroll
        for (int hd = 0; hd < 4; ++hd)
#pragma unroll
            for (int r = 0; r < 4; ++r) {
                int node = base + quad * 4 + r;
                es1[node * 4 + hd] = esp[hd * 4 + r];
                ed1[node * 4 + hd] = edp[hd * 4 + r];
            }
    }
#pragma unroll
    for (int nt = 0; nt < 16; ++nt)
#pragma unroll
        for (int r = 0; r < 4; ++r)
            h1[(size_t)(base + quad * 4 + r) * 256 + nt * 16 + col] = f2bf(acc[nt][r]);
}

// ---------------- GAT1 aggregate + bias + BN + ELU -> hb(bf16) ----------------
// wave per dst node (4/block); half-wave covers 256 ch (uint4 = 8 bf16/lane).
// No max-subtraction (scores bounded; alpha is shift-invariant). 8 edges in flight.

__global__ __launch_bounds__(256)
void k_gat1(const unsigned short* __restrict__ h1, const float* __restrict__ es1,
            const float* __restrict__ ed1, const int* __restrict__ offs,
            const int* __restrict__ csr, const float* __restrict__ b1,
            const float* __restrict__ g1, const float* __restrict__ be1,
            const float* __restrict__ m1, const float* __restrict__ v1,
            unsigned short* __restrict__ hb) {
    int wave = threadIdx.x >> 6, lane = threadIdx.x & 63;
    int d = blockIdx.x * 4 + wave;
    if (d >= N_NODES) return;
    int start = offs[d], deg = offs[d + 1] - start;
    int half = lane >> 5;
    int cg = lane & 31;
    int ch = cg * 8;
    int hc = cg >> 3;
    float edv = ed1[d * 4 + hc];
    float a[8];
#pragma unroll
    for (int k = 0; k < 8; ++k) a[k] = 0.f;
    float dn = 0.f;
    int j = 0;
#define ACC8(p, r) do { \
        a[0] += (p) * bf_lo((r).x); a[1] += (p) * bf_hi((r).x); \
        a[2] += (p) * bf_lo((r).y); a[3] += (p) * bf_hi((r).y); \
        a[4] += (p) * bf_lo((r).z); a[5] += (p) * bf_hi((r).z); \
        a[6] += (p) * bf_lo((r).w); a[7] += (p) * bf_hi((r).w); } while (0)
    for (; j + 8 <= deg; j += 8) {
        int s0 = csr[start + j + half];
        int s1 = csr[start + j + 2 + half];
        int s2 = csr[start + j + 4 + half];
        int s3 = csr[start + j + 6 + half];
        float e0 = es1[s0 * 4 + hc] + edv;
        float e1 = es1[s1 * 4 + hc] + edv;
        float e2 = es1[s2 * 4 + hc] + edv;
        float e3 = es1[s3 * 4 + hc] + edv;
        uint4 r0 = *(const uint4*)&h1[(size_t)s0 * 256 + ch];
        uint4 r1 = *(const uint4*)&h1[(size_t)s1 * 256 + ch];
        uint4 r2 = *(const uint4*)&h1[(size_t)s2 * 256 + ch];
        uint4 r3 = *(const uint4*)&h1[(size_t)s3 * 256 + ch];
        float p0 = __expf(leaky(e0));
        float p1 = __expf(leaky(e1));
        float p2 = __expf(leaky(e2));
        float p3 = __expf(leaky(e3));
        dn += (p0 + p1) + (p2 + p3);
        ACC8(p0, r0); ACC8(p1, r1); ACC8(p2, r2); ACC8(p3, r3);
    }
    for (; j + 2 <= deg; j += 2) {
        int s0 = csr[start + j + half];
        float e0 = es1[s0 * 4 + hc] + edv;
        uint4 r0 = *(const uint4*)&h1[(size_t)s0 * 256 + ch];
        float p0 = __expf(leaky(e0));
        dn += p0;
        ACC8(p0, r0);
    }
    if (j < deg && half == 0) {
        int s0 = csr[start + j];
        float e0 = es1[s0 * 4 + hc] + edv;
        uint4 r0 = *(const uint4*)&h1[(size_t)s0 * 256 + ch];
        float p0 = __expf(leaky(e0));
        dn += p0;
        ACC8(p0, r0);
    }
#undef ACC8
    dn += __shfl_xor(dn, 32);
#pragma unroll
    for (int k = 0; k < 8; ++k) a[k] += __shfl_xor(a[k], 32);
    float inv = 1.f / dn;
    int c = ch + half * 4;
    int ao = half * 4;
    float4 bv = *(const float4*)&b1[c];
    float4 gv = *(const float4*)&g1[c];
    float4 ev = *(const float4*)&be1[c];
    float4 mv = *(const float4*)&m1[c];
    float4 vv = *(const float4*)&v1[c];
    float o0 = a[ao + 0] * inv + bv.x, o1 = a[ao + 1] * inv + bv.y;
    float o2 = a[ao + 2] * inv + bv.z, o3 = a[ao + 3] * inv + bv.w;
    o0 = (o0 - mv.x) * rsqrtf(vv.x + EPS_BN) * gv.x + ev.x;
    o1 = (o1 - mv.y) * rsqrtf(vv.y + EPS_BN) * gv.y + ev.y;
    o2 = (o2 - mv.z) * rsqrtf(vv.z + EPS_BN) * gv.z + ev.z;
    o3 = (o3 - mv.w) * rsqrtf(vv.w + EPS_BN) * gv.w + ev.w;
    o0 = (o0 > 0.f) ? o0 : expm1f(o0);
    o1 = (o1 > 0.f) ? o1 : expm1f(o1);
    o2 = (o2 > 0.f) ? o2 : expm1f(o2);
    o3 = (o3 > 0.f) ? o3 : expm1f(o3);
    ushort4 ov;
    ov.x = f2bf(o0); ov.y = f2bf(o1); ov.z = f2bf(o2); ov.w = f2bf(o3);
    *(ushort4*)&hb[(size_t)d * 256 + c] = ov;
}

// ---------------- GEMM2 (MFMA): h2(bf16) = hb @ W2, scores es2/ed2 ----------------

__global__ __launch_bounds__(256)
void k_gemm2(const unsigned short* __restrict__ hbbf, const unsigned short* __restrict__ W2Tg,
             const float* __restrict__ a_s, const float* __restrict__ a_d,
             unsigned short* __restrict__ h2, float* __restrict__ es2, float* __restrict__ ed2) {
    __shared__ unsigned short W2T[64 * 264];
    int t = threadIdx.x;
    for (int c = t; c < 2048; c += 256) {            // 2048 chunks of 8 bf16
        int n = c >> 5, k8 = (c & 31) * 8;
        *(short8*)&W2T[n * 264 + k8] = *(const short8*)&W2Tg[n * 256 + k8];
    }
    __syncthreads();
    int wid = t >> 6, lane = t & 63;
    int quad = lane >> 4, col = lane & 15;
    float as_r[4], ad_r[4];
#pragma unroll
    for (int i = 0; i < 4; ++i) {
        as_r[i] = a_s[i * 16 + col];
        ad_r[i] = a_d[i * 16 + col];
    }
    int tile = blockIdx.x * 4 + wid;
    if (tile >= 3125) return;
    int base = tile * 16;
    short8 af[8];
#pragma unroll
    for (int kk = 0; kk < 8; ++kk)
        af[kk] = *(const short8*)&hbbf[(size_t)(base + col) * 256 + kk * 32 + quad * 8];
    f32x4 acc[4];
#pragma unroll
    for (int nt = 0; nt < 4; ++nt) acc[nt] = (f32x4){0.f, 0.f, 0.f, 0.f};
#pragma unroll
    for (int kk = 0; kk < 8; ++kk) {
#pragma unroll
        for (int nt = 0; nt < 4; ++nt) {
            short8 b = *(const short8*)&W2T[(nt * 16 + col) * 264 + kk * 32 + quad * 8];
            acc[nt] = __builtin_amdgcn_mfma_f32_16x16x32_bf16(af[kk], b, acc[nt], 0, 0, 0);
        }
    }
    float esp[4], edp[4];
#pragma unroll
    for (int r = 0; r < 4; ++r) { esp[r] = 0.f; edp[r] = 0.f; }
#pragma unroll
    for (int nt = 0; nt < 4; ++nt)
#pragma unroll
        for (int r = 0; r < 4; ++r) {
            esp[r] += acc[nt][r] * as_r[nt];
            edp[r] += acc[nt][r] * ad_r[nt];
        }
#pragma unroll
    for (int r = 0; r < 4; ++r) {
        float v = esp[r], w = edp[r];
#pragma unroll
        for (int m = 1; m <= 8; m <<= 1) { v += __shfl_xor(v, m); w += __shfl_xor(w, m); }
        esp[r] = v; edp[r] = w;
    }
    if (col == 0) {
#pragma unroll
        for (int r = 0; r < 4; ++r) {
            int node = base + quad * 4 + r;
            es2[node] = esp[r];
            ed2[node] = edp[r];
        }
    }
#pragma unroll
    for (int nt = 0; nt < 4; ++nt)
#pragma unroll
        for (int r = 0; r < 4; ++r)
            h2[(size_t)(base + quad * 4 + r) * 64 + nt * 16 + col] = f2bf(acc[nt][r]);
}

// ---------------- GAT2 aggregate + bias + BN ----------------
// wave per dst node (4/block); half-wave covers 64 ch (uint = 2 bf16/lane).
// No max-subtraction; 8 edges in flight.

__global__ __launch_bounds__(256)
void k_gat2(const unsigned short* __restrict__ h2, const float* __restrict__ es2,
            const float* __restrict__ ed2, const int* __restrict__ offs,
            const int* __restrict__ csr, const float* __restrict__ b2,
            const float* __restrict__ g2, const float* __restrict__ be2,
            const float* __restrict__ m2, const float* __restrict__ v2,
            float* __restrict__ out2) {
    int wave = threadIdx.x >> 6, lane = threadIdx.x & 63;
    int d = blockIdx.x * 4 + wave;
    if (d >= N_NODES) return;
    int start = offs[d], deg = offs[d + 1] - start;
    float edv = ed2[d];
    int half = lane >> 5;
    int cg = lane & 31;
    int ch = cg * 2;
    float a0 = 0.f, a1 = 0.f, dn = 0.f;
    int j = 0;
    for (; j + 8 <= deg; j += 8) {
        int s0 = csr[start + j + half];
        int s1 = csr[start + j + 2 + half];
        int s2 = csr[start + j + 4 + half];
        int s3 = csr[start + j + 6 + half];
        float e0 = es2[s0] + edv;
        float e1 = es2[s1] + edv;
        float e2 = es2[s2] + edv;
        float e3 = es2[s3] + edv;
        unsigned r0 = *(const unsigned*)&h2[(size_t)s0 * 64 + ch];
        unsigned r1 = *(const unsigned*)&h2[(size_t)s1 * 64 + ch];
        unsigned r2 = *(const unsigned*)&h2[(size_t)s2 * 64 + ch];
        unsigned r3 = *(const unsigned*)&h2[(size_t)s3 * 64 + ch];
        float p0 = __expf(leaky(e0));
        float p1 = __expf(leaky(e1));
        float p2 = __expf(leaky(e2));
        float p3 = __expf(leaky(e3));
        dn += (p0 + p1) + (p2 + p3);
        a0 += p0 * bf_lo(r0); a1 += p0 * bf_hi(r0);
        a0 += p1 * bf_lo(r1); a1 += p1 * bf_hi(r1);
        a0 += p2 * bf_lo(r2); a1 += p2 * bf_hi(r2);
        a0 += p3 * bf_lo(r3); a1 += p3 * bf_hi(r3);
    }
    for (; j + 2 <= deg; j += 2) {
        int s0 = csr[start + j + half];
        float e0 = es2[s0] + edv;
        unsigned r0 = *(const unsigned*)&h2[(size_t)s0 * 64 + ch];
        float p0 = __expf(leaky(e0));
        dn += p0;
        a0 += p0 * bf_lo(r0); a1 += p0 * bf_hi(r0);
    }
    if (j < deg && half == 0) {
        int s0 = csr[start + j];
        float e0 = es2[s0] + edv;
        unsigned r0 = *(const unsigned*)&h2[(size_t)s0 * 64 + ch];
        float p0 = __expf(leaky(e0));
        dn += p0;
        a0 += p0 * bf_lo(r0); a1 += p0 * bf_hi(r0);
    }
    dn += __shfl_xor(dn, 32);
    a0 += __shfl_xor(a0, 32);
    a1 += __shfl_xor(a1, 32);
    if (half == 0) {
        float inv = 1.f / dn;
        float o0 = a0 * inv + b2[ch];
        float o1 = a1 * inv + b2[ch + 1];
        o0 = (o0 - m2[ch]) * rsqrtf(v2[ch] + EPS_BN) * g2[ch] + be2[ch];
        o1 = (o1 - m2[ch + 1]) * rsqrtf(v2[ch + 1] + EPS_BN) * g2[ch + 1] + be2[ch + 1];
        *(float2*)&out2[(size_t)d * 64 + ch] = make_float2(o0, o1);
    }
}

// ---------------- mean pool per graph ----------------

__device__ int lower_bound_i(const int* a, int n, int key) {
    int lo = 0, hi = n;
    while (lo < hi) {
        int mid = (lo + hi) >> 1;
        if (a[mid] < key) lo = mid + 1; else hi = mid;
    }
    return lo;
}

__global__ __launch_bounds__(256)
void k_pool(const float* __restrict__ out2, const int* __restrict__ batch,
            float* __restrict__ pooled) {
    int g = blockIdx.x;
    __shared__ int ssh[2];
    __shared__ float red[256];
    if (threadIdx.x == 0) {
        ssh[0] = lower_bound_i(batch, N_NODES, g);
        ssh[1] = lower_bound_i(batch, N_NODES, g + 1);
    }
    __syncthreads();
    int start = ssh[0], end = ssh[1];
    int t = threadIdx.x, sub = t >> 6, lane = t & 63;
    float acc = 0.f;
    for (int i = start + sub; i < end; i += 4) acc += out2[(size_t)i * 64 + lane];
    red[t] = acc; __syncthreads();
    if (t < 64) {
        float s = red[t] + red[t + 64] + red[t + 128] + red[t + 192];
        int cnt = end - start;
        pooled[g * 64 + t] = s / (float)((cnt > 0) ? cnt : 1);
    }
}

// ---------------- MLP head + log_softmax ----------------

__global__ void k_head(const float* __restrict__ pooled, const float* __restrict__ lw1,
                       const float* __restrict__ lb1, const float* __restrict__ lw2,
                       const float* __restrict__ lb2, float* __restrict__ out) {
    int g = threadIdx.x;
    if (g >= GGRAPHS) return;
    float p[64];
#pragma unroll
    for (int c = 0; c < 64; ++c) p[c] = pooled[g * 64 + c];
    float z0 = lb2[0], z1 = lb2[1], z2 = lb2[2];
    for (int j = 0; j < 32; ++j) {
        float hj = lb1[j];
#pragma unroll
        for (int c = 0; c < 64; ++c) hj += p[c] * lw1[c * 32 + j];
        hj = fmaxf(hj, 0.f);
        z0 += hj * lw2[j * 3 + 0];
        z1 += hj * lw2[j * 3 + 1];
        z2 += hj * lw2[j * 3 + 2];
    }
    float m = fmaxf(z0, fmaxf(z1, z2));
    float lse = logf(expf(z0 - m) + expf(z1 - m) + expf(z2 - m)) + m;
    out[g * 3 + 0] = z0 - lse;
    out[g * 3 + 1] = z1 - lse;
    out[g * 3 + 2] = z2 - lse;
}

// ---------------- launch ----------------

extern "C" void kernel_launch(void* const* d_in, const int* in_sizes, int n_in,
                              void* d_out, int out_size, void* d_ws, size_t ws_size,
                              hipStream_t stream) {
    (void)in_sizes; (void)n_in; (void)out_size; (void)ws_size;
    const float* x    = (const float*)d_in[0];
    const int*   ei   = (const int*)d_in[1];
    const int*   batch= (const int*)d_in[2];
    const float* W1   = (const float*)d_in[3];
    const float* a_s1 = (const float*)d_in[4];
    const float* a_d1 = (const float*)d_in[5];
    const float* b1   = (const float*)d_in[6];
    const float* g1   = (const float*)d_in[7];
    const float* be1  = (const float*)d_in[8];
    const float* m1   = (const float*)d_in[9];
    const float* v1   = (const float*)d_in[10];
    const float* W2   = (const float*)d_in[11];
    const float* a_s2 = (const float*)d_in[12];
    const float* a_d2 = (const float*)d_in[13];
    const float* b2   = (const float*)d_in[14];
    const float* g2   = (const float*)d_in[15];
    const float* be2  = (const float*)d_in[16];
    const float* m2   = (const float*)d_in[17];
    const float* v2   = (const float*)d_in[18];
    const float* lw1  = (const float*)d_in[19];
    const float* lb1  = (const float*)d_in[20];
    const float* lw2  = (const float*)d_in[21];
    const float* lb2  = (const float*)d_in[22];
    float* out = (float*)d_out;

    char* ws = (char*)d_ws;
    size_t off = 0;
    auto alloc = [&](size_t bytes) -> void* {
        void* p = ws + off;
        off += (bytes + 255) & ~(size_t)255;
        return p;
    };
    unsigned short* xbf = (unsigned short*)alloc((size_t)N_NODES * 64 * 2);   // bf16
    unsigned short* W1T = (unsigned short*)alloc((size_t)16384 * 2);          // bf16 [n][k]
    unsigned short* W2T = (unsigned short*)alloc((size_t)16384 * 2);          // bf16 [n][k]
    unsigned short* h1  = (unsigned short*)alloc((size_t)N_NODES * 256 * 2);  // bf16
    unsigned short* hb  = (unsigned short*)alloc((size_t)N_NODES * 256 * 2);  // bf16
    unsigned short* h2  = (unsigned short*)alloc((size_t)N_NODES * 64 * 2);   // bf16
    float* out2 = (float*)alloc((size_t)N_NODES * 64 * 4);
    float* es1  = (float*)alloc((size_t)N_NODES * 4 * 4);
    float* ed1  = (float*)alloc((size_t)N_NODES * 4 * 4);
    float* es2  = (float*)alloc((size_t)N_NODES * 4);
    float* ed2  = (float*)alloc((size_t)N_NODES * 4);
    float* pooled = (float*)alloc((size_t)GGRAPHS * 64 * 4);
    int*   cnt  = (int*)alloc((size_t)N_NODES * 4);
    int*   offs = (int*)alloc((size_t)(N_NODES + 1) * 4);
    int*   curs = (int*)alloc((size_t)N_NODES * 4);
    int*   csr  = (int*)alloc((size_t)ETOT * 4);
    int*   bsums= (int*)alloc(256 * 4);

    const int nscan = (N_NODES + 255) / 256;   // 196
    const int nedge = (ETOT + 255) / 256;      // 3321
    const int nprep = (XQ + 32768 + 255) / 256;
    const int ntileb = (3125 + 3) / 4;         // 782 blocks for MFMA gemms

    hipMemsetAsync(cnt, 0, (size_t)N_NODES * 4, stream);
    k_prep<<<nprep, 256, 0, stream>>>(x, W1, W2, xbf, W1T, W2T);
    k_hist<<<nedge, 256, 0, stream>>>(ei, cnt);
    k_scan_local<<<nscan, 256, 0, stream>>>(cnt, offs, bsums);
    k_scan_sums<<<1, 256, 0, stream>>>(bsums, nscan);
    k_scan_add<<<nscan, 256, 0, stream>>>(offs, curs, bsums);
    k_fill<<<nedge, 256, 0, stream>>>(ei, curs, csr);

    k_gemm1<<<ntileb, 256, 0, stream>>>(xbf, W1T, a_s1, a_d1, h1, es1, ed1);
    k_gat1<<<(N_NODES + 3) / 4, 256, 0, stream>>>(h1, es1, ed1, offs, csr, b1, g1, be1, m1, v1, hb);
    k_gemm2<<<ntileb, 256, 0, stream>>>(hb, W2T, a_s2, a_d2, h2, es2, ed2);
    k_gat2<<<(N_NODES + 3) / 4, 256, 0, stream>>>(h2, es2, ed2, offs, csr, b2, g2, be2, m2, v2, out2);
    k_pool<<<GGRAPHS, 256, 0, stream>>>(out2, batch, pooled);
    k_head<<<1, 64, 0, stream>>>(pooled, lw1, lb1, lw2, lb2, out);
}

// Round 6
// 394.902 us; speedup vs baseline: 1.7937x; 1.0144x over previous
//
#include <hip/hip_runtime.h>
#include <math.h>

#define N_NODES 50000
#define N_EDGES 800000
#define ETOT    (N_EDGES + N_NODES)   // self-loops appended
#define GGRAPHS 64
#define EPS_BN  1e-5f

typedef __attribute__((ext_vector_type(8))) short short8;
typedef __attribute__((ext_vector_type(4))) float f32x4;
typedef __attribute__((ext_vector_type(2))) float f32x2;

__device__ __forceinline__ unsigned short f2bf(float f) {
    union { float f; unsigned u; } v; v.f = f;
    unsigned r = v.u + 0x7fffu + ((v.u >> 16) & 1u);   // round-nearest-even
    return (unsigned short)(r >> 16);
}
__device__ __forceinline__ float leaky(float e) {
    return fmaxf(e, 0.2f * e);
}
// pack 4 f32 -> 4 fp8 (e4m3, OCP on gfx950)
__device__ __forceinline__ unsigned pack4_fp8(float a, float b, float c, float d) {
    int v = __builtin_amdgcn_cvt_pk_fp8_f32(a, b, 0, false);
    v = __builtin_amdgcn_cvt_pk_fp8_f32(c, d, v, true);
    return (unsigned)v;
}

// ---------------- CSR build ----------------

__global__ void k_hist(const int* __restrict__ ei, int* __restrict__ cnt) {
    int e = blockIdx.x * 256 + threadIdx.x;
    if (e >= ETOT) return;
    int d = (e < N_EDGES) ? ei[N_EDGES + e] : (e - N_EDGES);
    atomicAdd(&cnt[d], 1);
}

__global__ void k_scan_local(const int* __restrict__ cnt, int* __restrict__ offs,
                             int* __restrict__ bsums) {
    __shared__ int s[256];
    int t = threadIdx.x, idx = blockIdx.x * 256 + t;
    int v = (idx < N_NODES) ? cnt[idx] : 0;
    s[t] = v; __syncthreads();
    for (int d2 = 1; d2 < 256; d2 <<= 1) {
        int add = (t >= d2) ? s[t - d2] : 0;
        __syncthreads();
        s[t] += add;
        __syncthreads();
    }
    if (idx < N_NODES) offs[idx] = s[t] - v;       // local exclusive
    if (t == 255) bsums[blockIdx.x] = s[255];
}

__global__ void k_scan_sums(int* __restrict__ bsums, int nb) {
    __shared__ int s[256];
    int t = threadIdx.x;
    int v = (t < nb) ? bsums[t] : 0;
    s[t] = v; __syncthreads();
    for (int d2 = 1; d2 < 256; d2 <<= 1) {
        int add = (t >= d2) ? s[t - d2] : 0;
        __syncthreads();
        s[t] += add;
        __syncthreads();
    }
    if (t < nb) bsums[t] = s[t] - v;               // exclusive
}

__global__ void k_scan_add(int* __restrict__ offs, int* __restrict__ cursor,
                           const int* __restrict__ bsums) {
    int idx = blockIdx.x * 256 + threadIdx.x;
    if (idx < N_NODES) {
        int o = offs[idx] + bsums[blockIdx.x];
        offs[idx] = o;
        cursor[idx] = o;
    }
    if (idx == 0) offs[N_NODES] = ETOT;
}

__global__ void k_fill(const int* __restrict__ ei, int* __restrict__ cursor,
                       int* __restrict__ csr) {
    int e = blockIdx.x * 256 + threadIdx.x;
    if (e >= ETOT) return;
    int s, d;
    if (e < N_EDGES) { s = ei[e]; d = ei[N_EDGES + e]; }
    else             { s = d = e - N_EDGES; }
    int pos = atomicAdd(&cursor[d], 1);
    csr[pos] = s;
}

// ---------------- prep: x->bf16, W1->W1T bf16, W2->W2T bf16 (perm rows) ----

#define XQ (N_NODES * 64 / 4)

__global__ void k_prep(const float* __restrict__ x, const float* __restrict__ W1,
                       const float* __restrict__ W2,
                       unsigned short* __restrict__ xbf,
                       unsigned short* __restrict__ W1T,
                       unsigned short* __restrict__ W2T) {
    int t = blockIdx.x * 256 + threadIdx.x;
    if (t < XQ) {
        float4 v = *(const float4*)&x[t * 4];
        ushort4 o;
        o.x = f2bf(v.x); o.y = f2bf(v.y); o.z = f2bf(v.z); o.w = f2bf(v.w);
        *(ushort4*)&xbf[t * 4] = o;
    } else if (t < XQ + 16384) {
        int i = t - XQ;                 // W1T[n*64+k] = W1[k*256+n]
        int n = i >> 6, k = i & 63;
        W1T[i] = f2bf(W1[k * 256 + n]);
    } else if (t < XQ + 32768) {
        int i = t - XQ - 16384;         // W2T[n*256+k'] = W2[real(k')*64+n]
        int n = i >> 8, kp = i & 255;
        int rk = (kp & 15) * 16 + (kp >> 4);   // hb slot k' holds real channel rk
        W2T[i] = f2bf(W2[rk * 64 + n]);
    }
}

// ---------------- GEMM1 (MFMA): h1(fp8, perm layout) = x @ W1, scores ----------
// h1 slot s of a row holds real channel (s&15)*16 + (s>>4).

__global__ __launch_bounds__(256)
void k_gemm1(const unsigned short* __restrict__ xbf, const unsigned short* __restrict__ W1Tg,
             const float* __restrict__ a_s, const float* __restrict__ a_d,
             unsigned char* __restrict__ h1f8, float* __restrict__ es1, float* __restrict__ ed1) {
    __shared__ unsigned short W1T[256 * 72];
    int t = threadIdx.x;
    for (int c = t; c < 2048; c += 256) {            // 2048 chunks of 8 bf16
        int n = c >> 3, k8 = (c & 7) * 8;
        *(short8*)&W1T[n * 72 + k8] = *(const short8*)&W1Tg[n * 64 + k8];
    }
    __syncthreads();
    int wid = t >> 6, lane = t & 63;
    int quad = lane >> 4, col = lane & 15;
    float as_r[16], ad_r[16];
#pragma unroll
    for (int i = 0; i < 16; ++i) {
        as_r[i] = a_s[i * 16 + col];
        ad_r[i] = a_d[i * 16 + col];
    }
    int tile = blockIdx.x * 4 + wid;
    if (tile >= 3125) return;
    int base = tile * 16;
    short8 a0 = *(const short8*)&xbf[(size_t)(base + col) * 64 + quad * 8];
    short8 a1 = *(const short8*)&xbf[(size_t)(base + col) * 64 + 32 + quad * 8];
    f32x4 acc[16];
#pragma unroll
    for (int nt = 0; nt < 16; ++nt) acc[nt] = (f32x4){0.f, 0.f, 0.f, 0.f};
#pragma unroll
    for (int nt = 0; nt < 16; ++nt) {
        short8 b0 = *(const short8*)&W1T[(nt * 16 + col) * 72 + quad * 8];
        short8 b1 = *(const short8*)&W1T[(nt * 16 + col) * 72 + 32 + quad * 8];
        acc[nt] = __builtin_amdgcn_mfma_f32_16x16x32_bf16(a0, b0, acc[nt], 0, 0, 0);
        acc[nt] = __builtin_amdgcn_mfma_f32_16x16x32_bf16(a1, b1, acc[nt], 0, 0, 0);
    }
    float esp[16], edp[16];
#pragma unroll
    for (int i = 0; i < 16; ++i) { esp[i] = 0.f; edp[i] = 0.f; }
#pragma unroll
    for (int nt = 0; nt < 16; ++nt) {
        int hd = nt >> 2;
#pragma unroll
        for (int r = 0; r < 4; ++r) {
            esp[hd * 4 + r] += acc[nt][r] * as_r[nt];
            edp[hd * 4 + r] += acc[nt][r] * ad_r[nt];
        }
    }
#pragma unroll
    for (int i = 0; i < 16; ++i) {
        float v = esp[i], w = edp[i];
#pragma unroll
        for (int m = 1; m <= 8; m <<= 1) { v += __shfl_xor(v, m); w += __shfl_xor(w, m); }
        esp[i] = v; edp[i] = w;
    }
    if (col == 0) {
#pragma unroll
        for (int hd = 0; hd < 4; ++hd)
#pragma unroll
            for (int r = 0; r < 4; ++r) {
                int node = base + quad * 4 + r;
                es1[node * 4 + hd] = esp[hd * 4 + r];
                ed1[node * 4 + hd] = edp[hd * 4 + r];
            }
    }
    // h1 fp8 store, permuted: byte slot col*16+nt  (16B vector store per row)
#pragma unroll
    for (int r = 0; r < 4; ++r) {
        uint4 pk;
        pk.x = pack4_fp8(acc[0][r],  acc[1][r],  acc[2][r],  acc[3][r]);
        pk.y = pack4_fp8(acc[4][r],  acc[5][r],  acc[6][r],  acc[7][r]);
        pk.z = pack4_fp8(acc[8][r],  acc[9][r],  acc[10][r], acc[11][r]);
        pk.w = pack4_fp8(acc[12][r], acc[13][r], acc[14][r], acc[15][r]);
        *(uint4*)&h1f8[(size_t)(base + quad * 4 + r) * 256 + col * 16] = pk;
    }
}

// ---------------- GAT1: full wave per edge, fp8 rows (256 B) ----------------
// lane l owns byte slots l*4..l*4+3 = real channels ((l&3)*4+i)*16 + (l>>2),
// head = l&3 (constant per lane). dn complete per lane; no cross-lane combines.
// Output hb in bf16 permuted slot layout (gemm2's W2T matches).

__global__ __launch_bounds__(256)
void k_gat1(const unsigned char* __restrict__ h1f8, const float* __restrict__ es1,
            const float* __restrict__ ed1, const int* __restrict__ offs,
            const int* __restrict__ csr, const float* __restrict__ b1,
            const float* __restrict__ g1, const float* __restrict__ be1,
            const float* __restrict__ m1, const float* __restrict__ v1,
            unsigned short* __restrict__ hb) {
    int wave = threadIdx.x >> 6, lane = threadIdx.x & 63;
    int d = blockIdx.x * 4 + wave;
    if (d >= N_NODES) return;
    int start = offs[d], deg = offs[d + 1] - start;
    int hd = lane & 3;
    float edv = ed1[d * 4 + hd];
    const unsigned char* hrow = h1f8 + lane * 4;
    float a0 = 0.f, a1 = 0.f, a2 = 0.f, a3 = 0.f, dn = 0.f;
#define ACCP(p, r) do { \
        f32x2 lo = __builtin_amdgcn_cvt_pk_f32_fp8((int)(r), false); \
        f32x2 hi = __builtin_amdgcn_cvt_pk_f32_fp8((int)(r), true);  \
        a0 += (p) * lo.x; a1 += (p) * lo.y; a2 += (p) * hi.x; a3 += (p) * hi.y; } while (0)
    int j = 0;
    for (; j + 8 <= deg; j += 8) {
        int s0 = csr[start + j + 0], s1 = csr[start + j + 1];
        int s2 = csr[start + j + 2], s3 = csr[start + j + 3];
        int s4 = csr[start + j + 4], s5 = csr[start + j + 5];
        int s6 = csr[start + j + 6], s7 = csr[start + j + 7];
        float e0 = es1[s0 * 4 + hd] + edv, e1 = es1[s1 * 4 + hd] + edv;
        float e2 = es1[s2 * 4 + hd] + edv, e3 = es1[s3 * 4 + hd] + edv;
        float e4 = es1[s4 * 4 + hd] + edv, e5 = es1[s5 * 4 + hd] + edv;
        float e6 = es1[s6 * 4 + hd] + edv, e7 = es1[s7 * 4 + hd] + edv;
        unsigned r0 = *(const unsigned*)(hrow + (size_t)s0 * 256);
        unsigned r1 = *(const unsigned*)(hrow + (size_t)s1 * 256);
        unsigned r2 = *(const unsigned*)(hrow + (size_t)s2 * 256);
        unsigned r3 = *(const unsigned*)(hrow + (size_t)s3 * 256);
        unsigned r4 = *(const unsigned*)(hrow + (size_t)s4 * 256);
        unsigned r5 = *(const unsigned*)(hrow + (size_t)s5 * 256);
        unsigned r6 = *(const unsigned*)(hrow + (size_t)s6 * 256);
        unsigned r7 = *(const unsigned*)(hrow + (size_t)s7 * 256);
        float p0 = __expf(leaky(e0)), p1 = __expf(leaky(e1));
        float p2 = __expf(leaky(e2)), p3 = __expf(leaky(e3));
        float p4 = __expf(leaky(e4)), p5 = __expf(leaky(e5));
        float p6 = __expf(leaky(e6)), p7 = __expf(leaky(e7));
        dn += ((p0 + p1) + (p2 + p3)) + ((p4 + p5) + (p6 + p7));
        ACCP(p0, r0); ACCP(p1, r1); ACCP(p2, r2); ACCP(p3, r3);
        ACCP(p4, r4); ACCP(p5, r5); ACCP(p6, r6); ACCP(p7, r7);
    }
    for (; j < deg; ++j) {
        int s0 = csr[start + j];
        float e0 = es1[s0 * 4 + hd] + edv;
        unsigned r0 = *(const unsigned*)(hrow + (size_t)s0 * 256);
        float p0 = __expf(leaky(e0));
        dn += p0;
        ACCP(p0, r0);
    }
#undef ACCP
    float inv = 1.f / dn;
    int rc = (lane & 3) * 64 + (lane >> 2);    // real channel for slot lane*4 (+i*16)
    float o0 = a0 * inv + b1[rc];
    float o1 = a1 * inv + b1[rc + 16];
    float o2 = a2 * inv + b1[rc + 32];
    float o3 = a3 * inv + b1[rc + 48];
    o0 = (o0 - m1[rc])      * rsqrtf(v1[rc]      + EPS_BN) * g1[rc]      + be1[rc];
    o1 = (o1 - m1[rc + 16]) * rsqrtf(v1[rc + 16] + EPS_BN) * g1[rc + 16] + be1[rc + 16];
    o2 = (o2 - m1[rc + 32]) * rsqrtf(v1[rc + 32] + EPS_BN) * g1[rc + 32] + be1[rc + 32];
    o3 = (o3 - m1[rc + 48]) * rsqrtf(v1[rc + 48] + EPS_BN) * g1[rc + 48] + be1[rc + 48];
    o0 = (o0 > 0.f) ? o0 : expm1f(o0);
    o1 = (o1 > 0.f) ? o1 : expm1f(o1);
    o2 = (o2 > 0.f) ? o2 : expm1f(o2);
    o3 = (o3 > 0.f) ? o3 : expm1f(o3);
    ushort4 ov;
    ov.x = f2bf(o0); ov.y = f2bf(o1); ov.z = f2bf(o2); ov.w = f2bf(o3);
    *(ushort4*)&hb[(size_t)d * 256 + lane * 4] = ov;   // permuted slot layout
}

// ---------------- GEMM2 (MFMA): h2(fp8, perm) = hb @ W2, scores es2/ed2 --------
// A = hb (permuted slots) matches W2T (perm rows); product is in real channels.
// h2 slot s of a row holds real channel (s&3)*16 + (s>>2).

__global__ __launch_bounds__(256)
void k_gemm2(const unsigned short* __restrict__ hbbf, const unsigned short* __restrict__ W2Tg,
             const float* __restrict__ a_s, const float* __restrict__ a_d,
             unsigned char* __restrict__ h2f8, float* __restrict__ es2, float* __restrict__ ed2) {
    __shared__ unsigned short W2T[64 * 264];
    int t = threadIdx.x;
    for (int c = t; c < 2048; c += 256) {            // 2048 chunks of 8 bf16
        int n = c >> 5, k8 = (c & 31) * 8;
        *(short8*)&W2T[n * 264 + k8] = *(const short8*)&W2Tg[n * 256 + k8];
    }
    __syncthreads();
    int wid = t >> 6, lane = t & 63;
    int quad = lane >> 4, col = lane & 15;
    float as_r[4], ad_r[4];
#pragma unroll
    for (int i = 0; i < 4; ++i) {
        as_r[i] = a_s[i * 16 + col];
        ad_r[i] = a_d[i * 16 + col];
    }
    int tile = blockIdx.x * 4 + wid;
    if (tile >= 3125) return;
    int base = tile * 16;
    short8 af[8];
#pragma unroll
    for (int kk = 0; kk < 8; ++kk)
        af[kk] = *(const short8*)&hbbf[(size_t)(base + col) * 256 + kk * 32 + quad * 8];
    f32x4 acc[4];
#pragma unroll
    for (int nt = 0; nt < 4; ++nt) acc[nt] = (f32x4){0.f, 0.f, 0.f, 0.f};
#pragma unroll
    for (int kk = 0; kk < 8; ++kk) {
#pragma unroll
        for (int nt = 0; nt < 4; ++nt) {
            short8 b = *(const short8*)&W2T[(nt * 16 + col) * 264 + kk * 32 + quad * 8];
            acc[nt] = __builtin_amdgcn_mfma_f32_16x16x32_bf16(af[kk], b, acc[nt], 0, 0, 0);
        }
    }
    float esp[4], edp[4];
#pragma unroll
    for (int r = 0; r < 4; ++r) { esp[r] = 0.f; edp[r] = 0.f; }
#pragma unroll
    for (int nt = 0; nt < 4; ++nt)
#pragma unroll
        for (int r = 0; r < 4; ++r) {
            esp[r] += acc[nt][r] * as_r[nt];
            edp[r] += acc[nt][r] * ad_r[nt];
        }
#pragma unroll
    for (int r = 0; r < 4; ++r) {
        float v = esp[r], w = edp[r];
#pragma unroll
        for (int m = 1; m <= 8; m <<= 1) { v += __shfl_xor(v, m); w += __shfl_xor(w, m); }
        esp[r] = v; edp[r] = w;
    }
    if (col == 0) {
#pragma unroll
        for (int r = 0; r < 4; ++r) {
            int node = base + quad * 4 + r;
            es2[node] = esp[r];
            ed2[node] = edp[r];
        }
    }
    // h2 fp8 store, permuted: byte slot col*4+nt (4B store per row)
#pragma unroll
    for (int r = 0; r < 4; ++r) {
        unsigned pk = pack4_fp8(acc[0][r], acc[1][r], acc[2][r], acc[3][r]);
        *(unsigned*)&h2f8[(size_t)(base + quad * 4 + r) * 64 + col * 4] = pk;
    }
}

// ---------------- GAT2: half-wave per edge, fp8 rows (64 B) ----------------
// lane cg owns byte slots cg*2, cg*2+1 = real channels r0, r0+16.
// out2 written in slot layout; k_head maps slots -> real for lw1.

__global__ __launch_bounds__(256)
void k_gat2(const unsigned char* __restrict__ h2f8, const float* __restrict__ es2,
            const float* __restrict__ ed2, const int* __restrict__ offs,
            const int* __restrict__ csr, const float* __restrict__ b2,
            const float* __restrict__ g2, const float* __restrict__ be2,
            const float* __restrict__ m2, const float* __restrict__ v2,
            float* __restrict__ out2) {
    int wave = threadIdx.x >> 6, lane = threadIdx.x & 63;
    int d = blockIdx.x * 4 + wave;
    if (d >= N_NODES) return;
    int start = offs[d], deg = offs[d + 1] - start;
    float edv = ed2[d];
    int half = lane >> 5;
    int cg = lane & 31;
    const unsigned char* hrow = h2f8 + cg * 2;
    float a0 = 0.f, a1 = 0.f, dn = 0.f;
    int j = 0;
    for (; j + 8 <= deg; j += 8) {
        int s0 = csr[start + j + half];
        int s1 = csr[start + j + 2 + half];
        int s2 = csr[start + j + 4 + half];
        int s3 = csr[start + j + 6 + half];
        float e0 = es2[s0] + edv, e1 = es2[s1] + edv;
        float e2 = es2[s2] + edv, e3 = es2[s3] + edv;
        int r0 = *(const unsigned short*)(hrow + (size_t)s0 * 64);
        int r1 = *(const unsigned short*)(hrow + (size_t)s1 * 64);
        int r2 = *(const unsigned short*)(hrow + (size_t)s2 * 64);
        int r3 = *(const unsigned short*)(hrow + (size_t)s3 * 64);
        float p0 = __expf(leaky(e0)), p1 = __expf(leaky(e1));
        float p2 = __expf(leaky(e2)), p3 = __expf(leaky(e3));
        dn += (p0 + p1) + (p2 + p3);
        f32x2 v0 = __builtin_amdgcn_cvt_pk_f32_fp8(r0, false);
        f32x2 v1 = __builtin_amdgcn_cvt_pk_f32_fp8(r1, false);
        f32x2 v2_ = __builtin_amdgcn_cvt_pk_f32_fp8(r2, false);
        f32x2 v3 = __builtin_amdgcn_cvt_pk_f32_fp8(r3, false);
        a0 += p0 * v0.x; a1 += p0 * v0.y;
        a0 += p1 * v1.x; a1 += p1 * v1.y;
        a0 += p2 * v2_.x; a1 += p2 * v2_.y;
        a0 += p3 * v3.x; a1 += p3 * v3.y;
    }
    for (; j + 2 <= deg; j += 2) {
        int s0 = csr[start + j + half];
        float e0 = es2[s0] + edv;
        int r0 = *(const unsigned short*)(hrow + (size_t)s0 * 64);
        float p0 = __expf(leaky(e0));
        dn += p0;
        f32x2 v0 = __builtin_amdgcn_cvt_pk_f32_fp8(r0, false);
        a0 += p0 * v0.x; a1 += p0 * v0.y;
    }
    if (j < deg && half == 0) {
        int s0 = csr[start + j];
        float e0 = es2[s0] + edv;
        int r0 = *(const unsigned short*)(hrow + (size_t)s0 * 64);
        float p0 = __expf(leaky(e0));
        dn += p0;
        f32x2 v0 = __builtin_amdgcn_cvt_pk_f32_fp8(r0, false);
        a0 += p0 * v0.x; a1 += p0 * v0.y;
    }
    dn += __shfl_xor(dn, 32);
    a0 += __shfl_xor(a0, 32);
    a1 += __shfl_xor(a1, 32);
    if (half == 0) {
        float inv = 1.f / dn;
        int s0slot = cg * 2;
        int r0 = (s0slot & 3) * 16 + (s0slot >> 2);  // real channel of slot cg*2
        int r1 = r0 + 16;                            // real channel of slot cg*2+1
        float o0 = a0 * inv + b2[r0];
        float o1 = a1 * inv + b2[r1];
        o0 = (o0 - m2[r0]) * rsqrtf(v2[r0] + EPS_BN) * g2[r0] + be2[r0];
        o1 = (o1 - m2[r1]) * rsqrtf(v2[r1] + EPS_BN) * g2[r1] + be2[r1];
        *(float2*)&out2[(size_t)d * 64 + cg * 2] = make_float2(o0, o1);
    }
}

// ---------------- mean pool per graph (slot layout, channel-agnostic) --------

__device__ int lower_bound_i(const int* a, int n, int key) {
    int lo = 0, hi = n;
    while (lo < hi) {
        int mid = (lo + hi) >> 1;
        if (a[mid] < key) lo = mid + 1; else hi = mid;
    }
    return lo;
}

__global__ __launch_bounds__(256)
void k_pool(const float* __restrict__ out2, const int* __restrict__ batch,
            float* __restrict__ pooled) {
    int g = blockIdx.x;
    __shared__ int ssh[2];
    __shared__ float red[256];
    if (threadIdx.x == 0) {
        ssh[0] = lower_bound_i(batch, N_NODES, g);
        ssh[1] = lower_bound_i(batch, N_NODES, g + 1);
    }
    __syncthreads();
    int start = ssh[0], end = ssh[1];
    int t = threadIdx.x, sub = t >> 6, lane = t & 63;
    float acc = 0.f;
    for (int i = start + sub; i < end; i += 4) acc += out2[(size_t)i * 64 + lane];
    red[t] = acc; __syncthreads();
    if (t < 64) {
        float s = red[t] + red[t + 64] + red[t + 128] + red[t + 192];
        int cnt = end - start;
        pooled[g * 64 + t] = s / (float)((cnt > 0) ? cnt : 1);
    }
}

// ---------------- MLP head + log_softmax (maps slots -> real channels) -------

__global__ void k_head(const float* __restrict__ pooled, const float* __restrict__ lw1,
                       const float* __restrict__ lb1, const float* __restrict__ lw2,
                       const float* __restrict__ lb2, float* __restrict__ out) {
    int g = threadIdx.x;
    if (g >= GGRAPHS) return;
    float p[64];
#pragma unroll
    for (int c = 0; c < 64; ++c) p[c] = pooled[g * 64 + c];
    float z0 = lb2[0], z1 = lb2[1], z2 = lb2[2];
    for (int j = 0; j < 32; ++j) {
        float hj = lb1[j];
#pragma unroll
        for (int c = 0; c < 64; ++c) {
            int rc = (c & 3) * 16 + (c >> 2);    // slot c holds real channel rc
            hj += p[c] * lw1[rc * 32 + j];
        }
        hj = fmaxf(hj, 0.f);
        z0 += hj * lw2[j * 3 + 0];
        z1 += hj * lw2[j * 3 + 1];
        z2 += hj * lw2[j * 3 + 2];
    }
    float m = fmaxf(z0, fmaxf(z1, z2));
    float lse = logf(expf(z0 - m) + expf(z1 - m) + expf(z2 - m)) + m;
    out[g * 3 + 0] = z0 - lse;
    out[g * 3 + 1] = z1 - lse;
    out[g * 3 + 2] = z2 - lse;
}

// ---------------- launch ----------------

extern "C" void kernel_launch(void* const* d_in, const int* in_sizes, int n_in,
                              void* d_out, int out_size, void* d_ws, size_t ws_size,
                              hipStream_t stream) {
    (void)in_sizes; (void)n_in; (void)out_size; (void)ws_size;
    const float* x    = (const float*)d_in[0];
    const int*   ei   = (const int*)d_in[1];
    const int*   batch= (const int*)d_in[2];
    const float* W1   = (const float*)d_in[3];
    const float* a_s1 = (const float*)d_in[4];
    const float* a_d1 = (const float*)d_in[5];
    const float* b1   = (const float*)d_in[6];
    const float* g1   = (const float*)d_in[7];
    const float* be1  = (const float*)d_in[8];
    const float* m1   = (const float*)d_in[9];
    const float* v1   = (const float*)d_in[10];
    const float* W2   = (const float*)d_in[11];
    const float* a_s2 = (const float*)d_in[12];
    const float* a_d2 = (const float*)d_in[13];
    const float* b2   = (const float*)d_in[14];
    const float* g2   = (const float*)d_in[15];
    const float* be2  = (const float*)d_in[16];
    const float* m2   = (const float*)d_in[17];
    const float* v2   = (const float*)d_in[18];
    const float* lw1  = (const float*)d_in[19];
    const float* lb1  = (const float*)d_in[20];
    const float* lw2  = (const float*)d_in[21];
    const float* lb2  = (const float*)d_in[22];
    float* out = (float*)d_out;

    char* ws = (char*)d_ws;
    size_t off = 0;
    auto alloc = [&](size_t bytes) -> void* {
        void* p = ws + off;
        off += (bytes + 255) & ~(size_t)255;
        return p;
    };
    unsigned short* xbf = (unsigned short*)alloc((size_t)N_NODES * 64 * 2);    // bf16
    unsigned short* W1T = (unsigned short*)alloc((size_t)16384 * 2);           // bf16 [n][k]
    unsigned short* W2T = (unsigned short*)alloc((size_t)16384 * 2);           // bf16 [n][k'] perm
    unsigned char*  h1  = (unsigned char*)alloc((size_t)N_NODES * 256);        // fp8 perm
    unsigned short* hb  = (unsigned short*)alloc((size_t)N_NODES * 256 * 2);   // bf16 perm slots
    unsigned char*  h2  = (unsigned char*)alloc((size_t)N_NODES * 64);         // fp8 perm
    float* out2 = (float*)alloc((size_t)N_NODES * 64 * 4);                     // f32 slot layout
    float* es1  = (float*)alloc((size_t)N_NODES * 4 * 4);
    float* ed1  = (float*)alloc((size_t)N_NODES * 4 * 4);
    float* es2  = (float*)alloc((size_t)N_NODES * 4);
    float* ed2  = (float*)alloc((size_t)N_NODES * 4);
    float* pooled = (float*)alloc((size_t)GGRAPHS * 64 * 4);
    int*   cnt  = (int*)alloc((size_t)N_NODES * 4);
    int*   offs = (int*)alloc((size_t)(N_NODES + 1) * 4);
    int*   curs = (int*)alloc((size_t)N_NODES * 4);
    int*   csr  = (int*)alloc((size_t)ETOT * 4);
    int*   bsums= (int*)alloc(256 * 4);

    const int nscan = (N_NODES + 255) / 256;   // 196
    const int nedge = (ETOT + 255) / 256;      // 3321
    const int nprep = (XQ + 32768 + 255) / 256;
    const int ntileb = (3125 + 3) / 4;         // 782 blocks for MFMA gemms

    hipMemsetAsync(cnt, 0, (size_t)N_NODES * 4, stream);
    k_prep<<<nprep, 256, 0, stream>>>(x, W1, W2, xbf, W1T, W2T);
    k_hist<<<nedge, 256, 0, stream>>>(ei, cnt);
    k_scan_local<<<nscan, 256, 0, stream>>>(cnt, offs, bsums);
    k_scan_sums<<<1, 256, 0, stream>>>(bsums, nscan);
    k_scan_add<<<nscan, 256, 0, stream>>>(offs, curs, bsums);
    k_fill<<<nedge, 256, 0, stream>>>(ei, curs, csr);

    k_gemm1<<<ntileb, 256, 0, stream>>>(xbf, W1T, a_s1, a_d1, h1, es1, ed1);
    k_gat1<<<(N_NODES + 3) / 4, 256, 0, stream>>>(h1, es1, ed1, offs, csr, b1, g1, be1, m1, v1, hb);
    k_gemm2<<<ntileb, 256, 0, stream>>>(hb, W2T, a_s2, a_d2, h2, es2, ed2);
    k_gat2<<<(N_NODES + 3) / 4, 256, 0, stream>>>(h2, es2, ed2, offs, csr, b2, g2, be2, m2, v2, out2);
    k_pool<<<GGRAPHS, 256, 0, stream>>>(out2, batch, pooled);
    k_head<<<1, 64, 0, stream>>>(pooled, lw1, lb1, lw2, lb2, out);
}